// Round 1
// baseline (803.898 us; speedup 1.0000x reference)
//
#include <hip/hip_runtime.h>
#include <hip/hip_bf16.h>

typedef __attribute__((ext_vector_type(4))) float f32x4;
typedef __attribute__((ext_vector_type(8))) short s16x8;
typedef unsigned short u16;

#define B_   2
#define L_   2048
#define D_   768
#define H_   12
#define HD_  64
#define LN_  1536   // merged length: 512 unm + 1024 dst
#define HID_ 3072

__device__ __forceinline__ u16 f2bf(float f) {
    union { float f; unsigned u; } v; v.f = f;
    unsigned r = (v.u + 0x7FFFu + ((v.u >> 16) & 1u)) >> 16;
    return (u16)r;
}

// ---------------- LayerNorm (row = 768) ----------------
__global__ __launch_bounds__(256) void ln_kernel(const float* __restrict__ x,
                                                 const float* __restrict__ g,
                                                 const float* __restrict__ bb,
                                                 float* __restrict__ hf,
                                                 u16* __restrict__ hb,
                                                 int storeF32) {
    __shared__ float sm[8];
    int row = blockIdx.x;
    const float* xr = x + (size_t)row * D_;
    int t = threadIdx.x;
    float4 v = make_float4(0.f, 0.f, 0.f, 0.f);
    float s = 0.f, s2 = 0.f;
    if (t < 192) {
        v = ((const float4*)xr)[t];
        s = v.x + v.y + v.z + v.w;
        s2 = v.x * v.x + v.y * v.y + v.z * v.z + v.w * v.w;
    }
    for (int o = 32; o; o >>= 1) { s += __shfl_down(s, o); s2 += __shfl_down(s2, o); }
    int wv = t >> 6, ln = t & 63;
    if (ln == 0) { sm[wv] = s; sm[4 + wv] = s2; }
    __syncthreads();
    if (t == 0) { sm[0] = sm[0] + sm[1] + sm[2] + sm[3]; sm[4] = sm[4] + sm[5] + sm[6] + sm[7]; }
    __syncthreads();
    float mu = sm[0] * (1.f / D_);
    float var = sm[4] * (1.f / D_) - mu * mu;
    float rs = rsqrtf(var + 1e-5f);
    if (t < 192) {
        float4 gg = ((const float4*)g)[t], bv = ((const float4*)bb)[t];
        float4 o;
        o.x = (v.x - mu) * rs * gg.x + bv.x;
        o.y = (v.y - mu) * rs * gg.y + bv.y;
        o.z = (v.z - mu) * rs * gg.z + bv.z;
        o.w = (v.w - mu) * rs * gg.w + bv.w;
        if (storeF32) ((float4*)(hf + (size_t)row * D_))[t] = o;
        ushort4 u;
        u.x = f2bf(o.x); u.y = f2bf(o.y); u.z = f2bf(o.z); u.w = f2bf(o.w);
        ((ushort4*)(hb + (size_t)row * D_))[t] = u;
    }
}

// ---------------- transpose + cast fp32(RxC) -> bf16(CxR) ----------------
__global__ void transpose_cast(const float* __restrict__ in, u16* __restrict__ out, int R, int C) {
    __shared__ float tile[32][33];
    int c0 = blockIdx.x * 32, r0 = blockIdx.y * 32;
    int tx = threadIdx.x, ty = threadIdx.y; // 32 x 8
    for (int i = 0; i < 32; i += 8)
        tile[ty + i][tx] = in[(size_t)(r0 + ty + i) * C + c0 + tx];
    __syncthreads();
    for (int i = 0; i < 32; i += 8)
        out[(size_t)(c0 + ty + i) * R + r0 + tx] = f2bf(tile[tx][ty + i]);
}

// ---------------- bf16 MFMA GEMM ----------------
// C[m][n] = sum_k A[m][k]*BT[n][k] + bias[n] (+resid[m][n]) (gelu?) -> f32 or bf16
// 128x128 tile, BK=64, 256 thr = 4 waves (2x2), wave = 64x64 (4x4 frags of 16x16x32)
#define BM 128
#define BN 128
#define BK 64
__global__ __launch_bounds__(256) void gemm_bf16(const u16* __restrict__ A, const u16* __restrict__ BT,
                                                 const float* __restrict__ bias,
                                                 const float* __restrict__ resid,
                                                 float* __restrict__ Cf, u16* __restrict__ Cb,
                                                 int M, int N, int K, int flags) {
    __shared__ __align__(16) u16 As[BM * BK];
    __shared__ __align__(16) u16 Bs[BN * BK];
    int tid = threadIdx.x;
    int wave = tid >> 6, lane = tid & 63;
    int wr = wave >> 1, wc = wave & 1;
    int mBase = blockIdx.y * BM, nBase = blockIdx.x * BN;
    int l15 = lane & 15, l4 = lane >> 4;
    f32x4 acc[4][4] = {};
    int nK = K / BK;
    for (int kt = 0; kt < nK; ++kt) {
        __syncthreads();
        #pragma unroll
        for (int i = 0; i < 4; ++i) {
            int cc = tid + 256 * i;          // 0..1023 chunks (16B each)
            int row = cc >> 3, sl = cc & 7;
            int gc = sl ^ (row & 7);         // inverse swizzle on global source
            const u16* ga = A + (size_t)(mBase + row) * K + kt * BK + gc * 8;
            *(uint4*)(&As[row * BK + sl * 8]) = *(const uint4*)ga;
            const u16* gb = BT + (size_t)(nBase + row) * K + kt * BK + gc * 8;
            *(uint4*)(&Bs[row * BK + sl * 8]) = *(const uint4*)gb;
        }
        __syncthreads();
        #pragma unroll
        for (int kk = 0; kk < 2; ++kk) {
            s16x8 af[4], bf[4];
            #pragma unroll
            for (int mi = 0; mi < 4; ++mi) {
                int row = wr * 64 + mi * 16 + l15;
                int ch = kk * 4 + l4;
                af[mi] = *(s16x8*)(&As[row * BK + (ch ^ (row & 7)) * 8]);
            }
            #pragma unroll
            for (int ni = 0; ni < 4; ++ni) {
                int row = wc * 64 + ni * 16 + l15;
                int ch = kk * 4 + l4;
                bf[ni] = *(s16x8*)(&Bs[row * BK + (ch ^ (row & 7)) * 8]);
            }
            #pragma unroll
            for (int mi = 0; mi < 4; ++mi)
                #pragma unroll
                for (int ni = 0; ni < 4; ++ni)
                    acc[mi][ni] = __builtin_amdgcn_mfma_f32_16x16x32_bf16(af[mi], bf[ni], acc[mi][ni], 0, 0, 0);
        }
    }
    // epilogue: D layout col=lane&15, row=(lane>>4)*4+reg
    #pragma unroll
    for (int mi = 0; mi < 4; ++mi) {
        #pragma unroll
        for (int j = 0; j < 4; ++j) {
            int row = mBase + wr * 64 + mi * 16 + l4 * 4 + j;
            #pragma unroll
            for (int ni = 0; ni < 4; ++ni) {
                int col = nBase + wc * 64 + ni * 16 + l15;
                float v = acc[mi][ni][j] + bias[col];
                if (resid) v += resid[(size_t)row * N + col];
                if (flags & 1) v = 0.5f * v * (1.f + erff(v * 0.70710678118654752f));
                if (flags & 2) Cb[(size_t)row * N + col] = f2bf(v);
                else Cf[(size_t)row * N + col] = v;
            }
        }
    }
}

// ---------------- build mean-of-head-blocks Wk / bk ----------------
__global__ void build_wkm(const float* __restrict__ Wqkv, const float* __restrict__ bqkv,
                          float* __restrict__ wkm /*[768][64]*/, float* __restrict__ bkm) {
    int idx = blockIdx.x * 256 + threadIdx.x;
    if (idx < D_ * HD_) {
        int k = idx >> 6, c = idx & 63;
        float s = 0.f;
        #pragma unroll
        for (int hh = 0; hh < H_; ++hh) s += Wqkv[(size_t)k * (3 * D_) + D_ + hh * HD_ + c];
        wkm[idx] = s * (1.f / H_);
    }
    if (idx < HD_) {
        float s = 0.f;
        #pragma unroll
        for (int hh = 0; hh < H_; ++hh) s += bqkv[D_ + hh * HD_ + idx];
        bkm[idx] = s * (1.f / H_);
    }
}

// ---------------- k_merge + normalize + even/odd split (fp32) ----------------
__global__ __launch_bounds__(256) void kmerge_kn(const float* __restrict__ hf, const float* __restrict__ wkm,
                                                 const float* __restrict__ bkm,
                                                 float* __restrict__ aset, float* __restrict__ bset) {
    __shared__ float wtile[256 * 64]; // 64KB
    int t = threadIdx.x, wave = t >> 6, lane = t & 63;
    int m0 = blockIdx.x * 16 + wave * 4;
    float acc[4] = {0.f, 0.f, 0.f, 0.f};
    for (int kc = 0; kc < 3; ++kc) {
        __syncthreads();
        for (int i = t; i < 256 * 64 / 4; i += 256)
            ((float4*)wtile)[i] = ((const float4*)(wkm + kc * 256 * 64))[i];
        __syncthreads();
        for (int k = 0; k < 256; ++k) {
            float wv = wtile[k * 64 + lane];
            #pragma unroll
            for (int r = 0; r < 4; ++r)
                acc[r] = fmaf(hf[(size_t)(m0 + r) * D_ + kc * 256 + k], wv, acc[r]);
        }
    }
    #pragma unroll
    for (int r = 0; r < 4; ++r) {
        float v = acc[r] + bkm[lane];
        float n2 = v * v;
        for (int o = 32; o; o >>= 1) n2 += __shfl_xor(n2, o);
        float kn = v / (sqrtf(n2) + 1e-8f);
        int m = m0 + r;
        int bb = m >> 11, l = m & 2047;
        float* dp = (l & 1) ? bset : aset;
        dp[((size_t)bb * 1024 + (l >> 1)) * 64 + lane] = kn;
    }
}

// ---------------- ToMe scores: rowwise max+argmax over 1024 cols ----------------
__global__ __launch_bounds__(256) void tome_scores(const float* __restrict__ aset, const float* __restrict__ bset,
                                                   float* __restrict__ node_max, int* __restrict__ node_idx) {
    __shared__ float aves[4][64];
    __shared__ unsigned long long wmax[4][4];
    int b = blockIdx.y;
    int a0 = blockIdx.x * 4;
    int t = threadIdx.x;
    { int r = t >> 6, d = t & 63; aves[r][d] = aset[((size_t)b * 1024 + a0 + r) * 64 + d]; }
    __syncthreads();
    unsigned long long best[4] = {0ull, 0ull, 0ull, 0ull};
    for (int c = t; c < 1024; c += 256) {
        const float4* brow = (const float4*)(bset + ((size_t)b * 1024 + c) * 64);
        float dot[4] = {0.f, 0.f, 0.f, 0.f};
        #pragma unroll
        for (int i = 0; i < 16; ++i) {
            float4 bv = brow[i];
            #pragma unroll
            for (int r = 0; r < 4; ++r) {
                dot[r] = fmaf(aves[r][4 * i + 0], bv.x, dot[r]);
                dot[r] = fmaf(aves[r][4 * i + 1], bv.y, dot[r]);
                dot[r] = fmaf(aves[r][4 * i + 2], bv.z, dot[r]);
                dot[r] = fmaf(aves[r][4 * i + 3], bv.w, dot[r]);
            }
        }
        #pragma unroll
        for (int r = 0; r < 4; ++r) {
            unsigned bits = __float_as_uint(dot[r]);
            unsigned u = (bits & 0x80000000u) ? ~bits : (bits | 0x80000000u);
            unsigned long long key = ((unsigned long long)u << 32) | (unsigned)(0xFFFFFFFFu - (unsigned)c);
            best[r] = best[r] > key ? best[r] : key;
        }
    }
    int wv = t >> 6, ln = t & 63;
    #pragma unroll
    for (int r = 0; r < 4; ++r) {
        unsigned long long v = best[r];
        for (int o = 32; o; o >>= 1) {
            unsigned long long w = __shfl_xor(v, o);
            v = v > w ? v : w;
        }
        if (ln == 0) wmax[r][wv] = v;
    }
    __syncthreads();
    if (t == 0) {
        for (int r = 0; r < 4; ++r) {
            int a = a0 + r;
            unsigned long long m = wmax[r][0];
            for (int w = 1; w < 4; ++w) m = m > wmax[r][w] ? m : wmax[r][w];
            float val; int idx;
            if (a == 0) { val = -INFINITY; idx = 0; }
            else {
                unsigned u = (unsigned)(m >> 32);
                unsigned bits = (u & 0x80000000u) ? (u ^ 0x80000000u) : ~u;
                val = __uint_as_float(bits);
                idx = (int)(0xFFFFFFFFu - (unsigned)(m & 0xFFFFFFFFu));
            }
            node_max[b * 1024 + a] = val;
            node_idx[b * 1024 + a] = idx;
        }
    }
}

// ---------------- stable argsort (desc value, asc idx) + unm sort ----------------
__global__ __launch_bounds__(512) void tome_sort(const float* __restrict__ node_max, const int* __restrict__ node_idx,
                                                 int* __restrict__ src_idx, int* __restrict__ dst_idx,
                                                 int* __restrict__ unm_idx) {
    __shared__ unsigned long long keys[1024];
    __shared__ int idxs[512];
    int b = blockIdx.x, t = threadIdx.x;
    for (int i = t; i < 1024; i += 512) {
        float v = node_max[b * 1024 + i];
        unsigned bits = __float_as_uint(v);
        unsigned u = (bits & 0x80000000u) ? ~bits : (bits | 0x80000000u);
        keys[i] = ((unsigned long long)(~u) << 32) | (unsigned)i; // ascending == desc value, asc idx
    }
    __syncthreads();
    for (int k = 2; k <= 1024; k <<= 1)
        for (int j = k >> 1; j > 0; j >>= 1) {
            for (int i = t; i < 1024; i += 512) {
                int ixj = i ^ j;
                if (ixj > i) {
                    bool up = (i & k) == 0;
                    unsigned long long a = keys[i], c = keys[ixj];
                    if (up ? (a > c) : (a < c)) { keys[i] = c; keys[ixj] = a; }
                }
            }
            __syncthreads();
        }
    {
        int s = (int)(keys[t] & 0xFFFFFFFFu);
        src_idx[b * 512 + t] = s;
        dst_idx[b * 512 + t] = node_idx[b * 1024 + s];
        idxs[t] = (int)(keys[512 + t] & 0xFFFFFFFFu);
    }
    __syncthreads();
    for (int k = 2; k <= 512; k <<= 1)
        for (int j = k >> 1; j > 0; j >>= 1) {
            int i = t, ixj = t ^ j;
            if (ixj > i) {
                bool up = (i & k) == 0;
                int a = idxs[i], c = idxs[ixj];
                if (up ? (a > c) : (a < c)) { idxs[i] = c; idxs[ixj] = a; }
            }
            __syncthreads();
        }
    unm_idx[b * 512 + t] = idxs[t];
}

// ---------------- windowed attention (fp32 VALU) ----------------
// block 128 thr = 2 waves; wave = 32 queries x 2 lanes (32 dims each)
__global__ __launch_bounds__(128) void attn_kernel(const float* __restrict__ qkv, const float* __restrict__ ts,
                                                   u16* __restrict__ ctx) {
    int qtile = blockIdx.x, h = blockIdx.y, b = blockIdx.z;
    int wave = threadIdx.x >> 6, lane = threadIdx.x & 63;
    int qi = lane >> 1, dh = lane & 1;
    int q0w = qtile * 64 + wave * 32;
    int q = q0w + qi;
    const float* qrow = qkv + (size_t)(b * L_ + q) * (3 * D_) + h * HD_ + dh * 32;
    float qv[32];
    #pragma unroll
    for (int i = 0; i < 8; ++i) {
        float4 v = ((const float4*)qrow)[i];
        qv[4 * i] = v.x; qv[4 * i + 1] = v.y; qv[4 * i + 2] = v.z; qv[4 * i + 3] = v.w;
    }
    int jlo = q0w - 128; if (jlo < 0) jlo = 0;
    int jhi = q0w + 159; if (jhi > L_ - 1) jhi = L_ - 1;
    float sum = 0.f;
    float o[32];
    #pragma unroll
    for (int i = 0; i < 32; ++i) o[i] = 0.f;
    for (int j = jlo; j <= jhi; ++j) {
        const float* krow = qkv + (size_t)(b * L_ + j) * (3 * D_) + D_ + h * HD_ + dh * 32;
        float part = 0.f;
        #pragma unroll
        for (int i = 0; i < 8; ++i) {
            float4 kv = ((const float4*)krow)[i];
            part = fmaf(qv[4 * i], kv.x, part);
            part = fmaf(qv[4 * i + 1], kv.y, part);
            part = fmaf(qv[4 * i + 2], kv.z, part);
            part = fmaf(qv[4 * i + 3], kv.w, part);
        }
        float score = part + __shfl_xor(part, 1);
        float tsj = ts[b * L_ + j];
        float logit = score * 0.125f + __logf(fmaxf(tsj, 1e-8f));
        int d = j - q;
        float p = (d >= -128 && d <= 128) ? __expf(logit) : 0.f;
        sum += p;
        const float* vrow = qkv + (size_t)(b * L_ + j) * (3 * D_) + 2 * D_ + h * HD_ + dh * 32;
        #pragma unroll
        for (int i = 0; i < 8; ++i) {
            float4 vv = ((const float4*)vrow)[i];
            o[4 * i]     = fmaf(p, vv.x, o[4 * i]);
            o[4 * i + 1] = fmaf(p, vv.y, o[4 * i + 1]);
            o[4 * i + 2] = fmaf(p, vv.z, o[4 * i + 2]);
            o[4 * i + 3] = fmaf(p, vv.w, o[4 * i + 3]);
        }
    }
    float inv = 1.f / sum;
    u16* crow = ctx + (size_t)(b * L_ + q) * D_ + h * HD_ + dh * 32;
    #pragma unroll
    for (int i = 0; i < 8; ++i) {
        ushort4 u;
        u.x = f2bf(o[4 * i] * inv); u.y = f2bf(o[4 * i + 1] * inv);
        u.z = f2bf(o[4 * i + 2] * inv); u.w = f2bf(o[4 * i + 3] * inv);
        ((ushort4*)crow)[i] = u;
    }
}

// ---------------- merge: init (unm copy + dst base) ----------------
__global__ __launch_bounds__(256) void merge_init(const float* __restrict__ xm, const float* __restrict__ ts,
                                                  const int* __restrict__ unm_idx,
                                                  float* __restrict__ x_sum, float* __restrict__ s_new) {
    int row = blockIdx.x;              // 0..B*LN_-1
    int b = row / LN_, rl = row % LN_;
    int srcTok = (rl < 512) ? (2 * unm_idx[b * 512 + rl]) : (2 * (rl - 512) + 1);
    float tsv = ts[b * L_ + srcTok];
    const float* src = xm + (size_t)(b * L_ + srcTok) * D_;
    float* dst = x_sum + (size_t)(b * LN_ + rl) * D_;
    int t = threadIdx.x;
    if (t < 192) {
        float4 v = ((const float4*)src)[t];
        v.x *= tsv; v.y *= tsv; v.z *= tsv; v.w *= tsv;
        ((float4*)dst)[t] = v;
    }
    if (t == 0) s_new[b * LN_ + rl] = tsv;
}

// ---------------- merge: scatter-add of merged sources ----------------
__global__ __launch_bounds__(256) void merge_scatter(const float* __restrict__ xm, const float* __restrict__ ts,
                                                     const int* __restrict__ src_idx, const int* __restrict__ dst_idx,
                                                     float* __restrict__ x_sum, float* __restrict__ s_new) {
    int e = blockIdx.x;                 // 0..B*512-1
    int b = e >> 9, el = e & 511;
    int s = src_idx[b * 512 + el];
    int dtok = dst_idx[b * 512 + el];
    int srcTok = 2 * s;
    float tsv = ts[b * L_ + srcTok];
    const float* src = xm + (size_t)(b * L_ + srcTok) * D_;
    float* dst = x_sum + (size_t)(b * LN_ + 512 + dtok) * D_;
    for (int i = threadIdx.x; i < D_; i += 256) atomicAdd(&dst[i], src[i] * tsv);
    if (threadIdx.x == 0) atomicAdd(&s_new[b * LN_ + 512 + dtok], tsv);
}

// ---------------- merge: divide by new token sizes (in place) ----------------
__global__ __launch_bounds__(256) void merge_div(float* __restrict__ x_sum, const float* __restrict__ s_new) {
    int row = blockIdx.x;
    float inv = 1.f / (s_new[row] + 1e-8f);
    float* p = x_sum + (size_t)row * D_;
    int t = threadIdx.x;
    if (t < 192) {
        float4 v = ((float4*)p)[t];
        v.x *= inv; v.y *= inv; v.z *= inv; v.w *= inv;
        ((float4*)p)[t] = v;
    }
}

extern "C" void kernel_launch(void* const* d_in, const int* in_sizes, int n_in,
                              void* d_out, int out_size, void* d_ws, size_t ws_size,
                              hipStream_t stream) {
    (void)in_sizes; (void)n_in; (void)out_size; (void)ws_size;
    const float* x     = (const float*)d_in[0];
    const float* ts    = (const float*)d_in[1];
    const float* ln1g  = (const float*)d_in[2];
    const float* ln1b  = (const float*)d_in[3];
    const float* ln2g  = (const float*)d_in[4];
    const float* ln2b  = (const float*)d_in[5];
    const float* Wqkv  = (const float*)d_in[6];
    const float* bqkv  = (const float*)d_in[7];
    const float* Wproj = (const float*)d_in[8];
    const float* bproj = (const float*)d_in[9];
    const float* W1    = (const float*)d_in[10];
    const float* b1    = (const float*)d_in[11];
    const float* W2    = (const float*)d_in[12];
    const float* b2    = (const float*)d_in[13];
    float* out = (float*)d_out;

    char* ws = (char*)d_ws;
    // offsets (bytes); regions reused where lifetimes don't overlap
    float* h_f32   = (float*)(ws + 0);            // 12582912  (reused as xm)
    u16*   h_bf16  = (u16*)(ws + 12582912);       // 6291456   (reused as ctx)
    float* qkv     = (float*)(ws + 18874368);     // 37748736  (reused as mid_bf16)
    float* x_new   = (float*)(ws + 56623104);     // 9437184
    float* s_new   = (float*)(ws + 66060288);     // 12288
    u16*   h2      = (u16*)(ws + 66072576);       // 4718592
    u16*   WqkvT   = (u16*)(ws + 70791168);       // 3538944
    u16*   WprojT  = (u16*)(ws + 74330112);       // 1179648
    u16*   W1T     = (u16*)(ws + 75509760);       // 4718592
    u16*   W2T     = (u16*)(ws + 80228352);       // 4718592
    float* wkm     = (float*)(ws + 84946944);     // 196608
    float* bkm     = (float*)(ws + 85143552);     // 256
    float* aset    = (float*)(ws + 85143808);     // 524288
    float* bset    = (float*)(ws + 85668096);     // 524288
    float* nmax    = (float*)(ws + 86192384);     // 8192
    int*   nidx    = (int*)(ws + 86200576);       // 8192
    int*   src_idx = (int*)(ws + 86208768);       // 4096
    int*   dst_idx = (int*)(ws + 86212864);       // 4096
    int*   unm_idx = (int*)(ws + 86216960);       // 4096
    float* xm  = h_f32;          // reuse after kmerge_kn consumed h_f32
    u16*   ctx = h_bf16;         // reuse after QKV GEMM consumed h_bf16
    u16*   mid = (u16*)qkv;      // reuse after attention consumed qkv

    // 1. LN1 -> h (f32 + bf16)
    ln_kernel<<<B_ * L_, 256, 0, stream>>>(x, ln1g, ln1b, h_f32, h_bf16, 1);
    // 2. mean-of-head-block Wk
    build_wkm<<<192, 256, 0, stream>>>(Wqkv, bqkv, wkm, bkm);
    // 3. transpose Wqkv -> [2304][768] bf16
    transpose_cast<<<dim3(3 * D_ / 32, D_ / 32), dim3(32, 8), 0, stream>>>(Wqkv, WqkvT, D_, 3 * D_);
    // 4. QKV GEMM (fp32 out)
    gemm_bf16<<<dim3(3 * D_ / BN, B_ * L_ / BM), 256, 0, stream>>>(
        h_bf16, WqkvT, bqkv, nullptr, qkv, nullptr, B_ * L_, 3 * D_, D_, 0);
    // 5. k_merge + normalize + even/odd split (fp32 exact path)
    kmerge_kn<<<B_ * L_ / 16, 256, 0, stream>>>(h_f32, wkm, bkm, aset, bset);
    // 6. ToMe scores -> node_max / node_idx
    tome_scores<<<dim3(256, B_), 256, 0, stream>>>(aset, bset, nmax, nidx);
    // 7. stable argsort -> src/dst/unm
    tome_sort<<<B_, 512, 0, stream>>>(nmax, nidx, src_idx, dst_idx, unm_idx);
    // 8. windowed attention -> ctx (bf16)
    attn_kernel<<<dim3(L_ / 64, H_, B_), 128, 0, stream>>>(qkv, ts, ctx);
    // 9. transpose Wproj
    transpose_cast<<<dim3(D_ / 32, D_ / 32), dim3(32, 8), 0, stream>>>(Wproj, WprojT, D_, D_);
    // 10. proj GEMM + residual x -> xm (fp32)
    gemm_bf16<<<dim3(D_ / BN, B_ * L_ / BM), 256, 0, stream>>>(
        ctx, WprojT, bproj, x, xm, nullptr, B_ * L_, D_, D_, 0);
    // 11-13. token merge
    merge_init<<<B_ * LN_, 256, 0, stream>>>(xm, ts, unm_idx, x_new, s_new);
    merge_scatter<<<B_ * 512, 256, 0, stream>>>(xm, ts, src_idx, dst_idx, x_new, s_new);
    merge_div<<<B_ * LN_, 256, 0, stream>>>(x_new, s_new);
    // 14. LN2 -> h2 (bf16)
    ln_kernel<<<B_ * LN_, 256, 0, stream>>>(x_new, ln2g, ln2b, nullptr, h2, 0);
    // 15. transpose W1
    transpose_cast<<<dim3(HID_ / 32, D_ / 32), dim3(32, 8), 0, stream>>>(W1, W1T, D_, HID_);
    // 16. MLP1 GEMM + gelu -> mid (bf16)
    gemm_bf16<<<dim3(HID_ / BN, B_ * LN_ / BM), 256, 0, stream>>>(
        h2, W1T, b1, nullptr, nullptr, mid, B_ * LN_, HID_, D_, 3);
    // 17. transpose W2
    transpose_cast<<<dim3(D_ / 32, HID_ / 32), dim3(32, 8), 0, stream>>>(W2, W2T, HID_, D_);
    // 18. MLP2 GEMM + residual x_new -> out (fp32)
    gemm_bf16<<<dim3(D_ / BN, B_ * LN_ / BM), 256, 0, stream>>>(
        mid, W2T, b2, x_new, out, nullptr, B_ * LN_, D_, HID_, 0);
}

// Round 2
// 377.885 us; speedup vs baseline: 2.1274x; 2.1274x over previous
//
#include <hip/hip_runtime.h>
#include <hip/hip_bf16.h>

typedef __attribute__((ext_vector_type(4))) float f32x4;
typedef __attribute__((ext_vector_type(8))) short s16x8;
typedef unsigned short u16;

#define B_   2
#define L_   2048
#define D_   768
#define H_   12
#define HD_  64
#define LN_  1536   // merged length: 512 unm + 1024 dst
#define HID_ 3072

__device__ __forceinline__ u16 f2bf(float f) {
    union { float f; unsigned u; } v; v.f = f;
    unsigned r = (v.u + 0x7FFFu + ((v.u >> 16) & 1u)) >> 16;
    return (u16)r;
}

// ---------------- LayerNorm (row = 768) ----------------
__global__ __launch_bounds__(256) void ln_kernel(const float* __restrict__ x,
                                                 const float* __restrict__ g,
                                                 const float* __restrict__ bb,
                                                 float* __restrict__ hf,
                                                 u16* __restrict__ hb,
                                                 int storeF32) {
    __shared__ float sm[8];
    int row = blockIdx.x;
    const float* xr = x + (size_t)row * D_;
    int t = threadIdx.x;
    float4 v = make_float4(0.f, 0.f, 0.f, 0.f);
    float s = 0.f, s2 = 0.f;
    if (t < 192) {
        v = ((const float4*)xr)[t];
        s = v.x + v.y + v.z + v.w;
        s2 = v.x * v.x + v.y * v.y + v.z * v.z + v.w * v.w;
    }
    for (int o = 32; o; o >>= 1) { s += __shfl_down(s, o); s2 += __shfl_down(s2, o); }
    int wv = t >> 6, ln = t & 63;
    if (ln == 0) { sm[wv] = s; sm[4 + wv] = s2; }
    __syncthreads();
    if (t == 0) { sm[0] = sm[0] + sm[1] + sm[2] + sm[3]; sm[4] = sm[4] + sm[5] + sm[6] + sm[7]; }
    __syncthreads();
    float mu = sm[0] * (1.f / D_);
    float var = sm[4] * (1.f / D_) - mu * mu;
    float rs = rsqrtf(var + 1e-5f);
    if (t < 192) {
        float4 gg = ((const float4*)g)[t], bv = ((const float4*)bb)[t];
        float4 o;
        o.x = (v.x - mu) * rs * gg.x + bv.x;
        o.y = (v.y - mu) * rs * gg.y + bv.y;
        o.z = (v.z - mu) * rs * gg.z + bv.z;
        o.w = (v.w - mu) * rs * gg.w + bv.w;
        if (storeF32) ((float4*)(hf + (size_t)row * D_))[t] = o;
        ushort4 u;
        u.x = f2bf(o.x); u.y = f2bf(o.y); u.z = f2bf(o.z); u.w = f2bf(o.w);
        ((ushort4*)(hb + (size_t)row * D_))[t] = u;
    }
}

// ---------------- transpose + cast fp32(RxC) -> bf16(CxR) ----------------
__global__ void transpose_cast(const float* __restrict__ in, u16* __restrict__ out, int R, int C) {
    __shared__ float tile[32][33];
    int c0 = blockIdx.x * 32, r0 = blockIdx.y * 32;
    int tx = threadIdx.x, ty = threadIdx.y; // 32 x 8
    for (int i = 0; i < 32; i += 8)
        tile[ty + i][tx] = in[(size_t)(r0 + ty + i) * C + c0 + tx];
    __syncthreads();
    for (int i = 0; i < 32; i += 8)
        out[(size_t)(c0 + ty + i) * R + r0 + tx] = f2bf(tile[tx][ty + i]);
}

// ---------------- bf16 MFMA GEMM ----------------
#define BM 128
#define BN 128
#define BK 64
__global__ __launch_bounds__(256) void gemm_bf16(const u16* __restrict__ A, const u16* __restrict__ BT,
                                                 const float* __restrict__ bias,
                                                 const float* __restrict__ resid,
                                                 float* __restrict__ Cf, u16* __restrict__ Cb,
                                                 int M, int N, int K, int flags) {
    __shared__ __align__(16) u16 As[BM * BK];
    __shared__ __align__(16) u16 Bs[BN * BK];
    int tid = threadIdx.x;
    int wave = tid >> 6, lane = tid & 63;
    int wr = wave >> 1, wc = wave & 1;
    int mBase = blockIdx.y * BM, nBase = blockIdx.x * BN;
    int l15 = lane & 15, l4 = lane >> 4;
    f32x4 acc[4][4] = {};
    int nK = K / BK;
    for (int kt = 0; kt < nK; ++kt) {
        __syncthreads();
        #pragma unroll
        for (int i = 0; i < 4; ++i) {
            int cc = tid + 256 * i;          // 0..1023 chunks (16B each)
            int row = cc >> 3, sl = cc & 7;
            int gc = sl ^ (row & 7);         // inverse swizzle on global source
            const u16* ga = A + (size_t)(mBase + row) * K + kt * BK + gc * 8;
            *(uint4*)(&As[row * BK + sl * 8]) = *(const uint4*)ga;
            const u16* gb = BT + (size_t)(nBase + row) * K + kt * BK + gc * 8;
            *(uint4*)(&Bs[row * BK + sl * 8]) = *(const uint4*)gb;
        }
        __syncthreads();
        #pragma unroll
        for (int kk = 0; kk < 2; ++kk) {
            s16x8 af[4], bf[4];
            #pragma unroll
            for (int mi = 0; mi < 4; ++mi) {
                int row = wr * 64 + mi * 16 + l15;
                int ch = kk * 4 + l4;
                af[mi] = *(s16x8*)(&As[row * BK + (ch ^ (row & 7)) * 8]);
            }
            #pragma unroll
            for (int ni = 0; ni < 4; ++ni) {
                int row = wc * 64 + ni * 16 + l15;
                int ch = kk * 4 + l4;
                bf[ni] = *(s16x8*)(&Bs[row * BK + (ch ^ (row & 7)) * 8]);
            }
            #pragma unroll
            for (int mi = 0; mi < 4; ++mi)
                #pragma unroll
                for (int ni = 0; ni < 4; ++ni)
                    acc[mi][ni] = __builtin_amdgcn_mfma_f32_16x16x32_bf16(af[mi], bf[ni], acc[mi][ni], 0, 0, 0);
        }
    }
    #pragma unroll
    for (int mi = 0; mi < 4; ++mi) {
        #pragma unroll
        for (int j = 0; j < 4; ++j) {
            int row = mBase + wr * 64 + mi * 16 + l4 * 4 + j;
            #pragma unroll
            for (int ni = 0; ni < 4; ++ni) {
                int col = nBase + wc * 64 + ni * 16 + l15;
                float v = acc[mi][ni][j] + bias[col];
                if (resid) v += resid[(size_t)row * N + col];
                if (flags & 1) v = 0.5f * v * (1.f + erff(v * 0.70710678118654752f));
                if (flags & 2) Cb[(size_t)row * N + col] = f2bf(v);
                else Cf[(size_t)row * N + col] = v;
            }
        }
    }
}

// ---------------- build mean-of-head-blocks Wk / bk ----------------
__global__ void build_wkm(const float* __restrict__ Wqkv, const float* __restrict__ bqkv,
                          float* __restrict__ wkm /*[768][64]*/, float* __restrict__ bkm) {
    int idx = blockIdx.x * 256 + threadIdx.x;
    if (idx < D_ * HD_) {
        int k = idx >> 6, c = idx & 63;
        float s = 0.f;
        #pragma unroll
        for (int hh = 0; hh < H_; ++hh) s += Wqkv[(size_t)k * (3 * D_) + D_ + hh * HD_ + c];
        wkm[idx] = s * (1.f / H_);
    }
    if (idx < HD_) {
        float s = 0.f;
        #pragma unroll
        for (int hh = 0; hh < H_; ++hh) s += bqkv[D_ + hh * HD_ + idx];
        bkm[idx] = s * (1.f / H_);
    }
}

// ---------------- k_merge + normalize + even/odd split (fp32) ----------------
__global__ __launch_bounds__(256) void kmerge_kn(const float* __restrict__ hf, const float* __restrict__ wkm,
                                                 const float* __restrict__ bkm,
                                                 float* __restrict__ aset, float* __restrict__ bset) {
    __shared__ float wtile[256 * 64]; // 64KB
    int t = threadIdx.x, wave = t >> 6, lane = t & 63;
    int m0 = blockIdx.x * 16 + wave * 4;
    float acc[4] = {0.f, 0.f, 0.f, 0.f};
    for (int kc = 0; kc < 3; ++kc) {
        __syncthreads();
        for (int i = t; i < 256 * 64 / 4; i += 256)
            ((float4*)wtile)[i] = ((const float4*)(wkm + kc * 256 * 64))[i];
        __syncthreads();
        for (int k = 0; k < 256; ++k) {
            float wv = wtile[k * 64 + lane];
            #pragma unroll
            for (int r = 0; r < 4; ++r)
                acc[r] = fmaf(hf[(size_t)(m0 + r) * D_ + kc * 256 + k], wv, acc[r]);
        }
    }
    #pragma unroll
    for (int r = 0; r < 4; ++r) {
        float v = acc[r] + bkm[lane];
        float n2 = v * v;
        for (int o = 32; o; o >>= 1) n2 += __shfl_xor(n2, o);
        float kn = v / (sqrtf(n2) + 1e-8f);
        int m = m0 + r;
        int bb = m >> 11, l = m & 2047;
        float* dp = (l & 1) ? bset : aset;
        dp[((size_t)bb * 1024 + (l >> 1)) * 64 + lane] = kn;
    }
}

// ---------------- ToMe scores: rowwise max+argmax over 1024 cols ----------------
__global__ __launch_bounds__(256) void tome_scores(const float* __restrict__ aset, const float* __restrict__ bset,
                                                   float* __restrict__ node_max, int* __restrict__ node_idx) {
    __shared__ float aves[4][64];
    __shared__ unsigned long long wmax[4][4];
    int b = blockIdx.y;
    int a0 = blockIdx.x * 4;
    int t = threadIdx.x;
    { int r = t >> 6, d = t & 63; aves[r][d] = aset[((size_t)b * 1024 + a0 + r) * 64 + d]; }
    __syncthreads();
    unsigned long long best[4] = {0ull, 0ull, 0ull, 0ull};
    for (int c = t; c < 1024; c += 256) {
        const float4* brow = (const float4*)(bset + ((size_t)b * 1024 + c) * 64);
        float dot[4] = {0.f, 0.f, 0.f, 0.f};
        #pragma unroll
        for (int i = 0; i < 16; ++i) {
            float4 bv = brow[i];
            #pragma unroll
            for (int r = 0; r < 4; ++r) {
                dot[r] = fmaf(aves[r][4 * i + 0], bv.x, dot[r]);
                dot[r] = fmaf(aves[r][4 * i + 1], bv.y, dot[r]);
                dot[r] = fmaf(aves[r][4 * i + 2], bv.z, dot[r]);
                dot[r] = fmaf(aves[r][4 * i + 3], bv.w, dot[r]);
            }
        }
        #pragma unroll
        for (int r = 0; r < 4; ++r) {
            unsigned bits = __float_as_uint(dot[r]);
            unsigned u = (bits & 0x80000000u) ? ~bits : (bits | 0x80000000u);
            unsigned long long key = ((unsigned long long)u << 32) | (unsigned)(0xFFFFFFFFu - (unsigned)c);
            best[r] = best[r] > key ? best[r] : key;
        }
    }
    int wv = t >> 6, ln = t & 63;
    #pragma unroll
    for (int r = 0; r < 4; ++r) {
        unsigned long long v = best[r];
        for (int o = 32; o; o >>= 1) {
            unsigned long long w = __shfl_xor(v, o);
            v = v > w ? v : w;
        }
        if (ln == 0) wmax[r][wv] = v;
    }
    __syncthreads();
    if (t == 0) {
        for (int r = 0; r < 4; ++r) {
            int a = a0 + r;
            unsigned long long m = wmax[r][0];
            for (int w = 1; w < 4; ++w) m = m > wmax[r][w] ? m : wmax[r][w];
            float val; int idx;
            if (a == 0) { val = -INFINITY; idx = 0; }
            else {
                unsigned u = (unsigned)(m >> 32);
                unsigned bits = (u & 0x80000000u) ? (u ^ 0x80000000u) : ~u;
                val = __uint_as_float(bits);
                idx = (int)(0xFFFFFFFFu - (unsigned)(m & 0xFFFFFFFFu));
            }
            node_max[b * 1024 + a] = val;
            node_idx[b * 1024 + a] = idx;
        }
    }
}

// ---------------- stable argsort (desc value, asc idx) + unm sort ----------------
__global__ __launch_bounds__(512) void tome_sort(const float* __restrict__ node_max, const int* __restrict__ node_idx,
                                                 int* __restrict__ src_idx, int* __restrict__ dst_idx,
                                                 int* __restrict__ unm_idx) {
    __shared__ unsigned long long keys[1024];
    __shared__ int idxs[512];
    int b = blockIdx.x, t = threadIdx.x;
    for (int i = t; i < 1024; i += 512) {
        float v = node_max[b * 1024 + i];
        unsigned bits = __float_as_uint(v);
        unsigned u = (bits & 0x80000000u) ? ~bits : (bits | 0x80000000u);
        keys[i] = ((unsigned long long)(~u) << 32) | (unsigned)i; // ascending == desc value, asc idx
    }
    __syncthreads();
    for (int k = 2; k <= 1024; k <<= 1)
        for (int j = k >> 1; j > 0; j >>= 1) {
            for (int i = t; i < 1024; i += 512) {
                int ixj = i ^ j;
                if (ixj > i) {
                    bool up = (i & k) == 0;
                    unsigned long long a = keys[i], c = keys[ixj];
                    if (up ? (a > c) : (a < c)) { keys[i] = c; keys[ixj] = a; }
                }
            }
            __syncthreads();
        }
    {
        int s = (int)(keys[t] & 0xFFFFFFFFu);
        src_idx[b * 512 + t] = s;
        dst_idx[b * 512 + t] = node_idx[b * 1024 + s];
        idxs[t] = (int)(keys[512 + t] & 0xFFFFFFFFu);
    }
    __syncthreads();
    for (int k = 2; k <= 512; k <<= 1)
        for (int j = k >> 1; j > 0; j >>= 1) {
            int i = t, ixj = t ^ j;
            if (ixj > i) {
                bool up = (i & k) == 0;
                int a = idxs[i], c = idxs[ixj];
                if (up ? (a > c) : (a < c)) { idxs[i] = c; idxs[ixj] = a; }
            }
            __syncthreads();
        }
    unm_idx[b * 512 + t] = idxs[t];
}

// ---------------- windowed attention via MFMA ----------------
// block = (qt, h, b): 64 queries, 4 waves x 16 queries. Window: 320 keys in 2 halves of 160.
// No online softmax: logits bounded, exp directly, divide at end.
__global__ __launch_bounds__(256) void attn_mfma(const float* __restrict__ qkv,
                                                 const float* __restrict__ ts,
                                                 u16* __restrict__ ctx) {
    __shared__ __align__(16) u16 Ks[160 * 64];      // XOR-swizzled [key][dim]
    __shared__ __align__(16) u16 Vt[64][168];       // [dim][key] pad->168
    __shared__ float lts[160];
    __shared__ __align__(16) u16 Pw[4][16 * 40];    // per-wave P round-trip, stride 40
    int qt = blockIdx.x, h = blockIdx.y, b = blockIdx.z;
    int tid = threadIdx.x, wave = tid >> 6, lane = tid & 63;
    int l15 = lane & 15, l4 = lane >> 4;
    int qbase = qt * 64 + wave * 16;
    int jbase0 = qt * 64 - 128;

    // Q fragments (A-operand): row=l15 (query), k=l4*8+j (dim)
    s16x8 qaf[2];
    {
        const float* qp = qkv + (size_t)(b * L_ + qbase + l15) * (3 * D_) + h * HD_;
        #pragma unroll
        for (int c = 0; c < 2; ++c) {
            const float* p = qp + c * 32 + l4 * 8;
            float4 v0 = ((const float4*)p)[0], v1 = ((const float4*)p)[1];
            s16x8 r;
            r[0] = f2bf(v0.x); r[1] = f2bf(v0.y); r[2] = f2bf(v0.z); r[3] = f2bf(v0.w);
            r[4] = f2bf(v1.x); r[5] = f2bf(v1.y); r[6] = f2bf(v1.z); r[7] = f2bf(v1.w);
            qaf[c] = r;
        }
    }
    f32x4 oacc[4] = {};
    float sums[4] = {0.f, 0.f, 0.f, 0.f};

    for (int half = 0; half < 2; ++half) {
        int jbase = jbase0 + half * 160;
        __syncthreads();
        // stage K (bf16, swizzled): 160 rows x 8 chunks of 8 elems
        #pragma unroll
        for (int i = 0; i < 5; ++i) {
            int cc = tid + 256 * i;
            int row = cc >> 3, sl = cc & 7;
            int gc = sl ^ (row & 7);
            int jc = min(max(jbase + row, 0), L_ - 1);
            const float* gp = qkv + (size_t)(b * L_ + jc) * (3 * D_) + D_ + h * HD_ + gc * 8;
            float4 v0 = ((const float4*)gp)[0], v1 = ((const float4*)gp)[1];
            s16x8 r;
            r[0] = f2bf(v0.x); r[1] = f2bf(v0.y); r[2] = f2bf(v0.z); r[3] = f2bf(v0.w);
            r[4] = f2bf(v1.x); r[5] = f2bf(v1.y); r[6] = f2bf(v1.z); r[7] = f2bf(v1.w);
            *(s16x8*)&Ks[row * 64 + sl * 8] = r;
        }
        // stage V transposed: [dim][key]
        #pragma unroll
        for (int i = 0; i < 10; ++i) {
            int idx = tid + 256 * i;
            int kk = idx >> 4, dc = (idx & 15) * 4;
            int jc = min(max(jbase + kk, 0), L_ - 1);
            const float* gp = qkv + (size_t)(b * L_ + jc) * (3 * D_) + 2 * D_ + h * HD_ + dc;
            float4 v = *(const float4*)gp;
            Vt[dc + 0][kk] = f2bf(v.x);
            Vt[dc + 1][kk] = f2bf(v.y);
            Vt[dc + 2][kk] = f2bf(v.z);
            Vt[dc + 3][kk] = f2bf(v.w);
        }
        if (tid < 160) {
            int jc = min(max(jbase + tid, 0), L_ - 1);
            lts[tid] = __logf(fmaxf(ts[b * L_ + jc], 1e-8f));
        }
        __syncthreads();
        // compute over 5 chunks of 32 keys
        #pragma unroll
        for (int kb = 0; kb < 5; ++kb) {
            #pragma unroll
            for (int f = 0; f < 2; ++f) {
                int kf16 = kb * 32 + f * 16;
                f32x4 s = {};
                #pragma unroll
                for (int c = 0; c < 2; ++c) {
                    int row = kf16 + l15;
                    int ch = (c * 4 + l4) ^ (row & 7);
                    s16x8 kf = *(const s16x8*)&Ks[row * 64 + ch * 8];
                    s = __builtin_amdgcn_mfma_f32_16x16x32_bf16(qaf[c], kf, s, 0, 0, 0);
                }
                int j = jbase + kf16 + l15;      // this lane's key column
                float lt = lts[kf16 + l15];
                #pragma unroll
                for (int jj = 0; jj < 4; ++jj) {
                    int q = qbase + l4 * 4 + jj;
                    int d = j - q;
                    bool ok = (j >= 0) && (j < L_) && (d >= -128) && (d <= 128);
                    float p = ok ? __expf(s[jj] * 0.125f + lt) : 0.f;
                    sums[jj] += p;
                    Pw[wave][(l4 * 4 + jj) * 40 + f * 16 + l15] = f2bf(p);
                }
            }
            asm volatile("s_waitcnt lgkmcnt(0)" ::: "memory");
            s16x8 paf = *(const s16x8*)&Pw[wave][l15 * 40 + l4 * 8];
            #pragma unroll
            for (int df = 0; df < 4; ++df) {
                s16x8 vbf = *(const s16x8*)&Vt[df * 16 + l15][kb * 32 + l4 * 8];
                oacc[df] = __builtin_amdgcn_mfma_f32_16x16x32_bf16(paf, vbf, oacc[df], 0, 0, 0);
            }
        }
    }
    // reduce denominators across the 16-lane column groups (rows = l4*4+jj)
    #pragma unroll
    for (int jj = 0; jj < 4; ++jj) {
        float s = sums[jj];
        s += __shfl_xor(s, 1); s += __shfl_xor(s, 2);
        s += __shfl_xor(s, 4); s += __shfl_xor(s, 8);
        sums[jj] = 1.f / s;
    }
    // store ctx bf16: row q=qbase+l4*4+jj, col d=df*16+l15
    #pragma unroll
    for (int jj = 0; jj < 4; ++jj) {
        int q = qbase + l4 * 4 + jj;
        u16* crow = ctx + (size_t)(b * L_ + q) * D_ + h * HD_;
        #pragma unroll
        for (int df = 0; df < 4; ++df)
            crow[df * 16 + l15] = f2bf(oacc[df][jj] * sums[jj]);
    }
}

// ---------------- merge: init (unm copy + dst base) ----------------
__global__ __launch_bounds__(256) void merge_init(const float* __restrict__ xm, const float* __restrict__ ts,
                                                  const int* __restrict__ unm_idx,
                                                  float* __restrict__ x_sum, float* __restrict__ s_new) {
    int row = blockIdx.x;              // 0..B*LN_-1
    int b = row / LN_, rl = row % LN_;
    int srcTok = (rl < 512) ? (2 * unm_idx[b * 512 + rl]) : (2 * (rl - 512) + 1);
    float tsv = ts[b * L_ + srcTok];
    const float* src = xm + (size_t)(b * L_ + srcTok) * D_;
    float* dst = x_sum + (size_t)(b * LN_ + rl) * D_;
    int t = threadIdx.x;
    if (t < 192) {
        float4 v = ((const float4*)src)[t];
        v.x *= tsv; v.y *= tsv; v.z *= tsv; v.w *= tsv;
        ((float4*)dst)[t] = v;
    }
    if (t == 0) s_new[b * LN_ + rl] = tsv;
}

// ---------------- merge: scatter-add of merged sources ----------------
__global__ __launch_bounds__(256) void merge_scatter(const float* __restrict__ xm, const float* __restrict__ ts,
                                                     const int* __restrict__ src_idx, const int* __restrict__ dst_idx,
                                                     float* __restrict__ x_sum, float* __restrict__ s_new) {
    int e = blockIdx.x;                 // 0..B*512-1
    int b = e >> 9, el = e & 511;
    int s = src_idx[b * 512 + el];
    int dtok = dst_idx[b * 512 + el];
    int srcTok = 2 * s;
    float tsv = ts[b * L_ + srcTok];
    const float* src = xm + (size_t)(b * L_ + srcTok) * D_;
    float* dst = x_sum + (size_t)(b * LN_ + 512 + dtok) * D_;
    for (int i = threadIdx.x; i < D_; i += 256) atomicAdd(&dst[i], src[i] * tsv);
    if (threadIdx.x == 0) atomicAdd(&s_new[b * LN_ + 512 + dtok], tsv);
}

// ---------------- merge: divide by new token sizes (in place) ----------------
__global__ __launch_bounds__(256) void merge_div(float* __restrict__ x_sum, const float* __restrict__ s_new) {
    int row = blockIdx.x;
    float inv = 1.f / (s_new[row] + 1e-8f);
    float* p = x_sum + (size_t)row * D_;
    int t = threadIdx.x;
    if (t < 192) {
        float4 v = ((float4*)p)[t];
        v.x *= inv; v.y *= inv; v.z *= inv; v.w *= inv;
        ((float4*)p)[t] = v;
    }
}

extern "C" void kernel_launch(void* const* d_in, const int* in_sizes, int n_in,
                              void* d_out, int out_size, void* d_ws, size_t ws_size,
                              hipStream_t stream) {
    (void)in_sizes; (void)n_in; (void)out_size; (void)ws_size;
    const float* x     = (const float*)d_in[0];
    const float* ts    = (const float*)d_in[1];
    const float* ln1g  = (const float*)d_in[2];
    const float* ln1b  = (const float*)d_in[3];
    const float* ln2g  = (const float*)d_in[4];
    const float* ln2b  = (const float*)d_in[5];
    const float* Wqkv  = (const float*)d_in[6];
    const float* bqkv  = (const float*)d_in[7];
    const float* Wproj = (const float*)d_in[8];
    const float* bproj = (const float*)d_in[9];
    const float* W1    = (const float*)d_in[10];
    const float* b1    = (const float*)d_in[11];
    const float* W2    = (const float*)d_in[12];
    const float* b2    = (const float*)d_in[13];
    float* out = (float*)d_out;

    char* ws = (char*)d_ws;
    float* h_f32   = (float*)(ws + 0);            // 12582912  (reused as xm)
    u16*   h_bf16  = (u16*)(ws + 12582912);       // 6291456   (reused as ctx)
    float* qkv     = (float*)(ws + 18874368);     // 37748736  (reused as mid_bf16)
    float* x_new   = (float*)(ws + 56623104);     // 9437184
    float* s_new   = (float*)(ws + 66060288);     // 12288
    u16*   h2      = (u16*)(ws + 66072576);       // 4718592
    u16*   WqkvT   = (u16*)(ws + 70791168);       // 3538944
    u16*   WprojT  = (u16*)(ws + 74330112);       // 1179648
    u16*   W1T     = (u16*)(ws + 75509760);       // 4718592
    u16*   W2T     = (u16*)(ws + 80228352);       // 4718592
    float* wkm     = (float*)(ws + 84946944);     // 196608
    float* bkm     = (float*)(ws + 85143552);     // 256
    float* aset    = (float*)(ws + 85143808);     // 524288
    float* bset    = (float*)(ws + 85668096);     // 524288
    float* nmax    = (float*)(ws + 86192384);     // 8192
    int*   nidx    = (int*)(ws + 86200576);       // 8192
    int*   src_idx = (int*)(ws + 86208768);       // 4096
    int*   dst_idx = (int*)(ws + 86212864);       // 4096
    int*   unm_idx = (int*)(ws + 86216960);       // 4096
    float* xm  = h_f32;
    u16*   ctx = h_bf16;
    u16*   mid = (u16*)qkv;

    ln_kernel<<<B_ * L_, 256, 0, stream>>>(x, ln1g, ln1b, h_f32, h_bf16, 1);
    build_wkm<<<192, 256, 0, stream>>>(Wqkv, bqkv, wkm, bkm);
    transpose_cast<<<dim3(3 * D_ / 32, D_ / 32), dim3(32, 8), 0, stream>>>(Wqkv, WqkvT, D_, 3 * D_);
    gemm_bf16<<<dim3(3 * D_ / BN, B_ * L_ / BM), 256, 0, stream>>>(
        h_bf16, WqkvT, bqkv, nullptr, qkv, nullptr, B_ * L_, 3 * D_, D_, 0);
    kmerge_kn<<<B_ * L_ / 16, 256, 0, stream>>>(h_f32, wkm, bkm, aset, bset);
    tome_scores<<<dim3(256, B_), 256, 0, stream>>>(aset, bset, nmax, nidx);
    tome_sort<<<B_, 512, 0, stream>>>(nmax, nidx, src_idx, dst_idx, unm_idx);
    attn_mfma<<<dim3(L_ / 64, H_, B_), 256, 0, stream>>>(qkv, ts, ctx);
    transpose_cast<<<dim3(D_ / 32, D_ / 32), dim3(32, 8), 0, stream>>>(Wproj, WprojT, D_, D_);
    gemm_bf16<<<dim3(D_ / BN, B_ * L_ / BM), 256, 0, stream>>>(
        ctx, WprojT, bproj, x, xm, nullptr, B_ * L_, D_, D_, 0);
    merge_init<<<B_ * LN_, 256, 0, stream>>>(xm, ts, unm_idx, x_new, s_new);
    merge_scatter<<<B_ * 512, 256, 0, stream>>>(xm, ts, src_idx, dst_idx, x_new, s_new);
    merge_div<<<B_ * LN_, 256, 0, stream>>>(x_new, s_new);
    ln_kernel<<<B_ * LN_, 256, 0, stream>>>(x_new, ln2g, ln2b, nullptr, h2, 0);
    transpose_cast<<<dim3(HID_ / 32, D_ / 32), dim3(32, 8), 0, stream>>>(W1, W1T, D_, HID_);
    gemm_bf16<<<dim3(HID_ / BN, B_ * LN_ / BM), 256, 0, stream>>>(
        h2, W1T, b1, nullptr, nullptr, mid, B_ * LN_, HID_, D_, 3);
    transpose_cast<<<dim3(D_ / 32, HID_ / 32), dim3(32, 8), 0, stream>>>(W2, W2T, HID_, D_);
    gemm_bf16<<<dim3(D_ / BN, B_ * LN_ / BM), 256, 0, stream>>>(
        mid, W2T, b2, x_new, out, nullptr, B_ * LN_, D_, HID_, 0);
}

// Round 3
// 360.476 us; speedup vs baseline: 2.2301x; 1.0483x over previous
//
#include <hip/hip_runtime.h>
#include <hip/hip_bf16.h>

typedef __attribute__((ext_vector_type(4))) float f32x4;
typedef __attribute__((ext_vector_type(8))) short s16x8;
typedef unsigned short u16;

#define B_   2
#define L_   2048
#define D_   768
#define H_   12
#define HD_  64
#define LN_  1536   // merged length: 512 unm + 1024 dst
#define HID_ 3072

__device__ __forceinline__ u16 f2bf(float f) {
    union { float f; unsigned u; } v; v.f = f;
    unsigned r = (v.u + 0x7FFFu + ((v.u >> 16) & 1u)) >> 16;
    return (u16)r;
}

__device__ __forceinline__ void gload_lds16(const void* g, void* l) {
    __builtin_amdgcn_global_load_lds((const __attribute__((address_space(1))) void*)g,
                                     (__attribute__((address_space(3))) void*)l, 16, 0, 0);
}

// ---------------- LayerNorm (row = 768) ----------------
__global__ __launch_bounds__(256) void ln_kernel(const float* __restrict__ x,
                                                 const float* __restrict__ g,
                                                 const float* __restrict__ bb,
                                                 float* __restrict__ hf,
                                                 u16* __restrict__ hb,
                                                 int storeF32) {
    __shared__ float sm[8];
    int row = blockIdx.x;
    const float* xr = x + (size_t)row * D_;
    int t = threadIdx.x;
    float4 v = make_float4(0.f, 0.f, 0.f, 0.f);
    float s = 0.f, s2 = 0.f;
    if (t < 192) {
        v = ((const float4*)xr)[t];
        s = v.x + v.y + v.z + v.w;
        s2 = v.x * v.x + v.y * v.y + v.z * v.z + v.w * v.w;
    }
    for (int o = 32; o; o >>= 1) { s += __shfl_down(s, o); s2 += __shfl_down(s2, o); }
    int wv = t >> 6, ln = t & 63;
    if (ln == 0) { sm[wv] = s; sm[4 + wv] = s2; }
    __syncthreads();
    if (t == 0) { sm[0] = sm[0] + sm[1] + sm[2] + sm[3]; sm[4] = sm[4] + sm[5] + sm[6] + sm[7]; }
    __syncthreads();
    float mu = sm[0] * (1.f / D_);
    float var = sm[4] * (1.f / D_) - mu * mu;
    float rs = rsqrtf(var + 1e-5f);
    if (t < 192) {
        float4 gg = ((const float4*)g)[t], bv = ((const float4*)bb)[t];
        float4 o;
        o.x = (v.x - mu) * rs * gg.x + bv.x;
        o.y = (v.y - mu) * rs * gg.y + bv.y;
        o.z = (v.z - mu) * rs * gg.z + bv.z;
        o.w = (v.w - mu) * rs * gg.w + bv.w;
        if (storeF32) ((float4*)(hf + (size_t)row * D_))[t] = o;
        ushort4 u;
        u.x = f2bf(o.x); u.y = f2bf(o.y); u.z = f2bf(o.z); u.w = f2bf(o.w);
        ((ushort4*)(hb + (size_t)row * D_))[t] = u;
    }
}

// ---------------- transpose + cast fp32(RxC) -> bf16(CxR) ----------------
__global__ void transpose_cast(const float* __restrict__ in, u16* __restrict__ out, int R, int C) {
    __shared__ float tile[32][33];
    int c0 = blockIdx.x * 32, r0 = blockIdx.y * 32;
    int tx = threadIdx.x, ty = threadIdx.y; // 32 x 8
    for (int i = 0; i < 32; i += 8)
        tile[ty + i][tx] = in[(size_t)(r0 + ty + i) * C + c0 + tx];
    __syncthreads();
    for (int i = 0; i < 32; i += 8)
        out[(size_t)(c0 + ty + i) * R + r0 + tx] = f2bf(tile[tx][ty + i]);
}

// ---------------- init output with bias (+resid) for split-K atomic GEMM ----------------
__global__ __launch_bounds__(256) void init_out(const float* __restrict__ bias,
                                                const float* __restrict__ resid,
                                                float* __restrict__ out, int N4, int total4) {
    int i = blockIdx.x * 256 + threadIdx.x;
    if (i < total4) {
        float4 bv = ((const float4*)bias)[i % N4];
        if (resid) {
            float4 r = ((const float4*)resid)[i];
            bv.x += r.x; bv.y += r.y; bv.z += r.z; bv.w += r.w;
        }
        ((float4*)out)[i] = bv;
    }
}

// ---------------- bf16 MFMA GEMM ----------------
// KS = gridDim.z splits of K; KS>1 -> unsafeAtomicAdd into preinitialized Cf.
#define BM 128
#define BN 128
#define BK 64
__global__ __launch_bounds__(256) void gemm_bf16(const u16* __restrict__ A, const u16* __restrict__ BT,
                                                 const float* __restrict__ bias,
                                                 const float* __restrict__ resid,
                                                 float* __restrict__ Cf, u16* __restrict__ Cb,
                                                 int M, int N, int K, int flags) {
    __shared__ __align__(16) u16 As[BM * BK];
    __shared__ __align__(16) u16 Bs[BN * BK];
    int tid = threadIdx.x;
    int wave = tid >> 6, lane = tid & 63;
    int wr = wave >> 1, wc = wave & 1;
    int mBase = blockIdx.y * BM, nBase = blockIdx.x * BN;
    int l15 = lane & 15, l4 = lane >> 4;
    f32x4 acc[4][4] = {};
    int Ksplit = K / gridDim.z;
    int kt0 = (blockIdx.z * Ksplit) / BK, kt1 = kt0 + Ksplit / BK;
    int lrow = lane >> 3, lsl = lane & 7;
    for (int kt = kt0; kt < kt1; ++kt) {
        __syncthreads();
        size_t koff = (size_t)kt * BK;
        #pragma unroll
        for (int i = 0; i < 4; ++i) {
            int rbase = wave * 32 + i * 8;
            int row = rbase + lrow;
            int gc = lsl ^ (row & 7);
            gload_lds16(A + (size_t)(mBase + row) * K + koff + gc * 8, &As[rbase * BK]);
            gload_lds16(BT + (size_t)(nBase + row) * K + koff + gc * 8, &Bs[rbase * BK]);
        }
        __syncthreads();
        #pragma unroll
        for (int kk = 0; kk < 2; ++kk) {
            s16x8 af[4], bf[4];
            #pragma unroll
            for (int mi = 0; mi < 4; ++mi) {
                int row = wr * 64 + mi * 16 + l15;
                int ch = kk * 4 + l4;
                af[mi] = *(s16x8*)(&As[row * BK + (ch ^ (row & 7)) * 8]);
            }
            #pragma unroll
            for (int ni = 0; ni < 4; ++ni) {
                int row = wc * 64 + ni * 16 + l15;
                int ch = kk * 4 + l4;
                bf[ni] = *(s16x8*)(&Bs[row * BK + (ch ^ (row & 7)) * 8]);
            }
            #pragma unroll
            for (int mi = 0; mi < 4; ++mi)
                #pragma unroll
                for (int ni = 0; ni < 4; ++ni)
                    acc[mi][ni] = __builtin_amdgcn_mfma_f32_16x16x32_bf16(af[mi], bf[ni], acc[mi][ni], 0, 0, 0);
        }
    }
    if (gridDim.z > 1) {
        // split-K: accumulate into preinitialized (bias+resid) fp32 output
        #pragma unroll
        for (int mi = 0; mi < 4; ++mi)
            #pragma unroll
            for (int j = 0; j < 4; ++j) {
                int row = mBase + wr * 64 + mi * 16 + l4 * 4 + j;
                #pragma unroll
                for (int ni = 0; ni < 4; ++ni) {
                    int col = nBase + wc * 64 + ni * 16 + l15;
                    unsafeAtomicAdd(&Cf[(size_t)row * N + col], acc[mi][ni][j]);
                }
            }
        return;
    }
    #pragma unroll
    for (int mi = 0; mi < 4; ++mi) {
        #pragma unroll
        for (int j = 0; j < 4; ++j) {
            int row = mBase + wr * 64 + mi * 16 + l4 * 4 + j;
            #pragma unroll
            for (int ni = 0; ni < 4; ++ni) {
                int col = nBase + wc * 64 + ni * 16 + l15;
                float v = acc[mi][ni][j] + bias[col];
                if (resid) v += resid[(size_t)row * N + col];
                if (flags & 1) v = 0.5f * v * (1.f + erff(v * 0.70710678118654752f));
                if (flags & 2) Cb[(size_t)row * N + col] = f2bf(v);
                else Cf[(size_t)row * N + col] = v;
            }
        }
    }
}

// ---------------- build mean-of-head-blocks Wk / bk ----------------
__global__ void build_wkm(const float* __restrict__ Wqkv, const float* __restrict__ bqkv,
                          float* __restrict__ wkm /*[768][64]*/, float* __restrict__ bkm) {
    int idx = blockIdx.x * 256 + threadIdx.x;
    if (idx < D_ * HD_) {
        int k = idx >> 6, c = idx & 63;
        float s = 0.f;
        #pragma unroll
        for (int hh = 0; hh < H_; ++hh) s += Wqkv[(size_t)k * (3 * D_) + D_ + hh * HD_ + c];
        wkm[idx] = s * (1.f / H_);
    }
    if (idx < HD_) {
        float s = 0.f;
        #pragma unroll
        for (int hh = 0; hh < H_; ++hh) s += bqkv[D_ + hh * HD_ + idx];
        bkm[idx] = s * (1.f / H_);
    }
}

// ---------------- k_merge + normalize + even/odd split (fp32) ----------------
__global__ __launch_bounds__(256) void kmerge_kn(const float* __restrict__ hf, const float* __restrict__ wkm,
                                                 const float* __restrict__ bkm,
                                                 float* __restrict__ aset, float* __restrict__ bset) {
    __shared__ float wtile[256 * 64]; // 64KB
    int t = threadIdx.x, wave = t >> 6, lane = t & 63;
    int m0 = blockIdx.x * 16 + wave * 4;
    float acc[4] = {0.f, 0.f, 0.f, 0.f};
    for (int kc = 0; kc < 3; ++kc) {
        __syncthreads();
        for (int i = t; i < 256 * 64 / 4; i += 256)
            ((float4*)wtile)[i] = ((const float4*)(wkm + kc * 256 * 64))[i];
        __syncthreads();
        for (int k = 0; k < 256; ++k) {
            float wv = wtile[k * 64 + lane];
            #pragma unroll
            for (int r = 0; r < 4; ++r)
                acc[r] = fmaf(hf[(size_t)(m0 + r) * D_ + kc * 256 + k], wv, acc[r]);
        }
    }
    #pragma unroll
    for (int r = 0; r < 4; ++r) {
        float v = acc[r] + bkm[lane];
        float n2 = v * v;
        for (int o = 32; o; o >>= 1) n2 += __shfl_xor(n2, o);
        float kn = v / (sqrtf(n2) + 1e-8f);
        int m = m0 + r;
        int bb = m >> 11, l = m & 2047;
        float* dp = (l & 1) ? bset : aset;
        dp[((size_t)bb * 1024 + (l >> 1)) * 64 + lane] = kn;
    }
}

// ---------------- ToMe scores: rowwise max+argmax over 1024 cols ----------------
__global__ __launch_bounds__(256) void tome_scores(const float* __restrict__ aset, const float* __restrict__ bset,
                                                   float* __restrict__ node_max, int* __restrict__ node_idx) {
    __shared__ float aves[4][64];
    __shared__ unsigned long long wmax[4][4];
    int b = blockIdx.y;
    int a0 = blockIdx.x * 4;
    int t = threadIdx.x;
    { int r = t >> 6, d = t & 63; aves[r][d] = aset[((size_t)b * 1024 + a0 + r) * 64 + d]; }
    __syncthreads();
    unsigned long long best[4] = {0ull, 0ull, 0ull, 0ull};
    for (int c = t; c < 1024; c += 256) {
        const float4* brow = (const float4*)(bset + ((size_t)b * 1024 + c) * 64);
        float dot[4] = {0.f, 0.f, 0.f, 0.f};
        #pragma unroll
        for (int i = 0; i < 16; ++i) {
            float4 bv = brow[i];
            #pragma unroll
            for (int r = 0; r < 4; ++r) {
                dot[r] = fmaf(aves[r][4 * i + 0], bv.x, dot[r]);
                dot[r] = fmaf(aves[r][4 * i + 1], bv.y, dot[r]);
                dot[r] = fmaf(aves[r][4 * i + 2], bv.z, dot[r]);
                dot[r] = fmaf(aves[r][4 * i + 3], bv.w, dot[r]);
            }
        }
        #pragma unroll
        for (int r = 0; r < 4; ++r) {
            unsigned bits = __float_as_uint(dot[r]);
            unsigned u = (bits & 0x80000000u) ? ~bits : (bits | 0x80000000u);
            unsigned long long key = ((unsigned long long)u << 32) | (unsigned)(0xFFFFFFFFu - (unsigned)c);
            best[r] = best[r] > key ? best[r] : key;
        }
    }
    int wv = t >> 6, ln = t & 63;
    #pragma unroll
    for (int r = 0; r < 4; ++r) {
        unsigned long long v = best[r];
        for (int o = 32; o; o >>= 1) {
            unsigned long long w = __shfl_xor(v, o);
            v = v > w ? v : w;
        }
        if (ln == 0) wmax[r][wv] = v;
    }
    __syncthreads();
    if (t == 0) {
        for (int r = 0; r < 4; ++r) {
            int a = a0 + r;
            unsigned long long m = wmax[r][0];
            for (int w = 1; w < 4; ++w) m = m > wmax[r][w] ? m : wmax[r][w];
            float val; int idx;
            if (a == 0) { val = -INFINITY; idx = 0; }
            else {
                unsigned u = (unsigned)(m >> 32);
                unsigned bits = (u & 0x80000000u) ? (u ^ 0x80000000u) : ~u;
                val = __uint_as_float(bits);
                idx = (int)(0xFFFFFFFFu - (unsigned)(m & 0xFFFFFFFFu));
            }
            node_max[b * 1024 + a] = val;
            node_idx[b * 1024 + a] = idx;
        }
    }
}

// ---------------- stable argsort (desc value, asc idx) + unm sort ----------------
__global__ __launch_bounds__(512) void tome_sort(const float* __restrict__ node_max, const int* __restrict__ node_idx,
                                                 int* __restrict__ src_idx, int* __restrict__ dst_idx,
                                                 int* __restrict__ unm_idx) {
    __shared__ unsigned long long keys[1024];
    __shared__ int idxs[512];
    int b = blockIdx.x, t = threadIdx.x;
    for (int i = t; i < 1024; i += 512) {
        float v = node_max[b * 1024 + i];
        unsigned bits = __float_as_uint(v);
        unsigned u = (bits & 0x80000000u) ? ~bits : (bits | 0x80000000u);
        keys[i] = ((unsigned long long)(~u) << 32) | (unsigned)i; // ascending == desc value, asc idx
    }
    __syncthreads();
    for (int k = 2; k <= 1024; k <<= 1)
        for (int j = k >> 1; j > 0; j >>= 1) {
            for (int i = t; i < 1024; i += 512) {
                int ixj = i ^ j;
                if (ixj > i) {
                    bool up = (i & k) == 0;
                    unsigned long long a = keys[i], c = keys[ixj];
                    if (up ? (a > c) : (a < c)) { keys[i] = c; keys[ixj] = a; }
                }
            }
            __syncthreads();
        }
    {
        int s = (int)(keys[t] & 0xFFFFFFFFu);
        src_idx[b * 512 + t] = s;
        dst_idx[b * 512 + t] = node_idx[b * 1024 + s];
        idxs[t] = (int)(keys[512 + t] & 0xFFFFFFFFu);
    }
    __syncthreads();
    for (int k = 2; k <= 512; k <<= 1)
        for (int j = k >> 1; j > 0; j >>= 1) {
            int i = t, ixj = t ^ j;
            if (ixj > i) {
                bool up = (i & k) == 0;
                int a = idxs[i], c = idxs[ixj];
                if (up ? (a > c) : (a < c)) { idxs[i] = c; idxs[ixj] = a; }
            }
            __syncthreads();
        }
    unm_idx[b * 512 + t] = idxs[t];
}

// ---------------- windowed attention via MFMA ----------------
__global__ __launch_bounds__(256) void attn_mfma(const float* __restrict__ qkv,
                                                 const float* __restrict__ ts,
                                                 u16* __restrict__ ctx) {
    __shared__ __align__(16) u16 Ks[160 * 64];      // XOR-swizzled [key][dim]
    __shared__ __align__(16) u16 Vt[64][168];       // [dim][key] pad->168
    __shared__ float lts[160];
    __shared__ __align__(16) u16 Pw[4][16 * 40];    // per-wave P round-trip, stride 40
    int qt = blockIdx.x, h = blockIdx.y, b = blockIdx.z;
    int tid = threadIdx.x, wave = tid >> 6, lane = tid & 63;
    int l15 = lane & 15, l4 = lane >> 4;
    int qbase = qt * 64 + wave * 16;
    int jbase0 = qt * 64 - 128;

    s16x8 qaf[2];
    {
        const float* qp = qkv + (size_t)(b * L_ + qbase + l15) * (3 * D_) + h * HD_;
        #pragma unroll
        for (int c = 0; c < 2; ++c) {
            const float* p = qp + c * 32 + l4 * 8;
            float4 v0 = ((const float4*)p)[0], v1 = ((const float4*)p)[1];
            s16x8 r;
            r[0] = f2bf(v0.x); r[1] = f2bf(v0.y); r[2] = f2bf(v0.z); r[3] = f2bf(v0.w);
            r[4] = f2bf(v1.x); r[5] = f2bf(v1.y); r[6] = f2bf(v1.z); r[7] = f2bf(v1.w);
            qaf[c] = r;
        }
    }
    f32x4 oacc[4] = {};
    float sums[4] = {0.f, 0.f, 0.f, 0.f};

    for (int half = 0; half < 2; ++half) {
        int jbase = jbase0 + half * 160;
        __syncthreads();
        #pragma unroll
        for (int i = 0; i < 5; ++i) {
            int cc = tid + 256 * i;
            int row = cc >> 3, sl = cc & 7;
            int gc = sl ^ (row & 7);
            int jc = min(max(jbase + row, 0), L_ - 1);
            const float* gp = qkv + (size_t)(b * L_ + jc) * (3 * D_) + D_ + h * HD_ + gc * 8;
            float4 v0 = ((const float4*)gp)[0], v1 = ((const float4*)gp)[1];
            s16x8 r;
            r[0] = f2bf(v0.x); r[1] = f2bf(v0.y); r[2] = f2bf(v0.z); r[3] = f2bf(v0.w);
            r[4] = f2bf(v1.x); r[5] = f2bf(v1.y); r[6] = f2bf(v1.z); r[7] = f2bf(v1.w);
            *(s16x8*)&Ks[row * 64 + sl * 8] = r;
        }
        #pragma unroll
        for (int i = 0; i < 10; ++i) {
            int idx = tid + 256 * i;
            int kk = idx >> 4, dc = (idx & 15) * 4;
            int jc = min(max(jbase + kk, 0), L_ - 1);
            const float* gp = qkv + (size_t)(b * L_ + jc) * (3 * D_) + 2 * D_ + h * HD_ + dc;
            float4 v = *(const float4*)gp;
            Vt[dc + 0][kk] = f2bf(v.x);
            Vt[dc + 1][kk] = f2bf(v.y);
            Vt[dc + 2][kk] = f2bf(v.z);
            Vt[dc + 3][kk] = f2bf(v.w);
        }
        if (tid < 160) {
            int jc = min(max(jbase + tid, 0), L_ - 1);
            lts[tid] = __logf(fmaxf(ts[b * L_ + jc], 1e-8f));
        }
        __syncthreads();
        #pragma unroll
        for (int kb = 0; kb < 5; ++kb) {
            #pragma unroll
            for (int f = 0; f < 2; ++f) {
                int kf16 = kb * 32 + f * 16;
                f32x4 s = {};
                #pragma unroll
                for (int c = 0; c < 2; ++c) {
                    int row = kf16 + l15;
                    int ch = (c * 4 + l4) ^ (row & 7);
                    s16x8 kf = *(const s16x8*)&Ks[row * 64 + ch * 8];
                    s = __builtin_amdgcn_mfma_f32_16x16x32_bf16(qaf[c], kf, s, 0, 0, 0);
                }
                int j = jbase + kf16 + l15;
                float lt = lts[kf16 + l15];
                #pragma unroll
                for (int jj = 0; jj < 4; ++jj) {
                    int q = qbase + l4 * 4 + jj;
                    int d = j - q;
                    bool ok = (j >= 0) && (j < L_) && (d >= -128) && (d <= 128);
                    float p = ok ? __expf(s[jj] * 0.125f + lt) : 0.f;
                    sums[jj] += p;
                    Pw[wave][(l4 * 4 + jj) * 40 + f * 16 + l15] = f2bf(p);
                }
            }
            asm volatile("s_waitcnt lgkmcnt(0)" ::: "memory");
            s16x8 paf = *(const s16x8*)&Pw[wave][l15 * 40 + l4 * 8];
            #pragma unroll
            for (int df = 0; df < 4; ++df) {
                s16x8 vbf = *(const s16x8*)&Vt[df * 16 + l15][kb * 32 + l4 * 8];
                oacc[df] = __builtin_amdgcn_mfma_f32_16x16x32_bf16(paf, vbf, oacc[df], 0, 0, 0);
            }
        }
    }
    #pragma unroll
    for (int jj = 0; jj < 4; ++jj) {
        float s = sums[jj];
        s += __shfl_xor(s, 1); s += __shfl_xor(s, 2);
        s += __shfl_xor(s, 4); s += __shfl_xor(s, 8);
        sums[jj] = 1.f / s;
    }
    #pragma unroll
    for (int jj = 0; jj < 4; ++jj) {
        int q = qbase + l4 * 4 + jj;
        u16* crow = ctx + (size_t)(b * L_ + q) * D_ + h * HD_;
        #pragma unroll
        for (int df = 0; df < 4; ++df)
            crow[df * 16 + l15] = f2bf(oacc[df][jj] * sums[jj]);
    }
}

// ---------------- merge kernels ----------------
__global__ __launch_bounds__(256) void merge_init(const float* __restrict__ xm, const float* __restrict__ ts,
                                                  const int* __restrict__ unm_idx,
                                                  float* __restrict__ x_sum, float* __restrict__ s_new) {
    int row = blockIdx.x;
    int b = row / LN_, rl = row % LN_;
    int srcTok = (rl < 512) ? (2 * unm_idx[b * 512 + rl]) : (2 * (rl - 512) + 1);
    float tsv = ts[b * L_ + srcTok];
    const float* src = xm + (size_t)(b * L_ + srcTok) * D_;
    float* dst = x_sum + (size_t)(b * LN_ + rl) * D_;
    int t = threadIdx.x;
    if (t < 192) {
        float4 v = ((const float4*)src)[t];
        v.x *= tsv; v.y *= tsv; v.z *= tsv; v.w *= tsv;
        ((float4*)dst)[t] = v;
    }
    if (t == 0) s_new[b * LN_ + rl] = tsv;
}

__global__ __launch_bounds__(256) void merge_scatter(const float* __restrict__ xm, const float* __restrict__ ts,
                                                     const int* __restrict__ src_idx, const int* __restrict__ dst_idx,
                                                     float* __restrict__ x_sum, float* __restrict__ s_new) {
    int e = blockIdx.x;
    int b = e >> 9, el = e & 511;
    int s = src_idx[b * 512 + el];
    int dtok = dst_idx[b * 512 + el];
    int srcTok = 2 * s;
    float tsv = ts[b * L_ + srcTok];
    const float* src = xm + (size_t)(b * L_ + srcTok) * D_;
    float* dst = x_sum + (size_t)(b * LN_ + 512 + dtok) * D_;
    for (int i = threadIdx.x; i < D_; i += 256) atomicAdd(&dst[i], src[i] * tsv);
    if (threadIdx.x == 0) atomicAdd(&s_new[b * LN_ + 512 + dtok], tsv);
}

__global__ __launch_bounds__(256) void merge_div(float* __restrict__ x_sum, const float* __restrict__ s_new) {
    int row = blockIdx.x;
    float inv = 1.f / (s_new[row] + 1e-8f);
    float* p = x_sum + (size_t)row * D_;
    int t = threadIdx.x;
    if (t < 192) {
        float4 v = ((float4*)p)[t];
        v.x *= inv; v.y *= inv; v.z *= inv; v.w *= inv;
        ((float4*)p)[t] = v;
    }
}

extern "C" void kernel_launch(void* const* d_in, const int* in_sizes, int n_in,
                              void* d_out, int out_size, void* d_ws, size_t ws_size,
                              hipStream_t stream) {
    (void)in_sizes; (void)n_in; (void)out_size; (void)ws_size;
    const float* x     = (const float*)d_in[0];
    const float* ts    = (const float*)d_in[1];
    const float* ln1g  = (const float*)d_in[2];
    const float* ln1b  = (const float*)d_in[3];
    const float* ln2g  = (const float*)d_in[4];
    const float* ln2b  = (const float*)d_in[5];
    const float* Wqkv  = (const float*)d_in[6];
    const float* bqkv  = (const float*)d_in[7];
    const float* Wproj = (const float*)d_in[8];
    const float* bproj = (const float*)d_in[9];
    const float* W1    = (const float*)d_in[10];
    const float* b1    = (const float*)d_in[11];
    const float* W2    = (const float*)d_in[12];
    const float* b2    = (const float*)d_in[13];
    float* out = (float*)d_out;

    char* ws = (char*)d_ws;
    float* h_f32   = (float*)(ws + 0);            // 12582912  (reused as xm)
    u16*   h_bf16  = (u16*)(ws + 12582912);       // 6291456   (reused as ctx)
    float* qkv     = (float*)(ws + 18874368);     // 37748736  (reused as mid_bf16)
    float* x_new   = (float*)(ws + 56623104);     // 9437184
    float* s_new   = (float*)(ws + 66060288);     // 12288
    u16*   h2      = (u16*)(ws + 66072576);       // 4718592
    u16*   WqkvT   = (u16*)(ws + 70791168);       // 3538944
    u16*   WprojT  = (u16*)(ws + 74330112);       // 1179648
    u16*   W1T     = (u16*)(ws + 75509760);       // 4718592
    u16*   W2T     = (u16*)(ws + 80228352);       // 4718592
    float* wkm     = (float*)(ws + 84946944);     // 196608
    float* bkm     = (float*)(ws + 85143552);     // 256
    float* aset    = (float*)(ws + 85143808);     // 524288
    float* bset    = (float*)(ws + 85668096);     // 524288
    float* nmax    = (float*)(ws + 86192384);     // 8192
    int*   nidx    = (int*)(ws + 86200576);       // 8192
    int*   src_idx = (int*)(ws + 86208768);       // 4096
    int*   dst_idx = (int*)(ws + 86212864);       // 4096
    int*   unm_idx = (int*)(ws + 86216960);       // 4096
    float* xm  = h_f32;
    u16*   ctx = h_bf16;
    u16*   mid = (u16*)qkv;

    ln_kernel<<<B_ * L_, 256, 0, stream>>>(x, ln1g, ln1b, h_f32, h_bf16, 1);
    build_wkm<<<192, 256, 0, stream>>>(Wqkv, bqkv, wkm, bkm);
    transpose_cast<<<dim3(3 * D_ / 32, D_ / 32), dim3(32, 8), 0, stream>>>(Wqkv, WqkvT, D_, 3 * D_);
    // QKV GEMM (no split)
    gemm_bf16<<<dim3(3 * D_ / BN, B_ * L_ / BM, 1), 256, 0, stream>>>(
        h_bf16, WqkvT, bqkv, nullptr, qkv, nullptr, B_ * L_, 3 * D_, D_, 0);
    kmerge_kn<<<B_ * L_ / 16, 256, 0, stream>>>(h_f32, wkm, bkm, aset, bset);
    tome_scores<<<dim3(256, B_), 256, 0, stream>>>(aset, bset, nmax, nidx);
    tome_sort<<<B_, 512, 0, stream>>>(nmax, nidx, src_idx, dst_idx, unm_idx);
    attn_mfma<<<dim3(L_ / 64, H_, B_), 256, 0, stream>>>(qkv, ts, ctx);
    transpose_cast<<<dim3(D_ / 32, D_ / 32), dim3(32, 8), 0, stream>>>(Wproj, WprojT, D_, D_);
    // proj GEMM: split-K=2, out preinit with bproj + x
    init_out<<<(B_ * L_ * D_ / 4 + 255) / 256, 256, 0, stream>>>(bproj, x, xm, D_ / 4, B_ * L_ * D_ / 4);
    gemm_bf16<<<dim3(D_ / BN, B_ * L_ / BM, 2), 256, 0, stream>>>(
        ctx, WprojT, bproj, nullptr, xm, nullptr, B_ * L_, D_, D_, 0);
    merge_init<<<B_ * LN_, 256, 0, stream>>>(xm, ts, unm_idx, x_new, s_new);
    merge_scatter<<<B_ * 512, 256, 0, stream>>>(xm, ts, src_idx, dst_idx, x_new, s_new);
    merge_div<<<B_ * LN_, 256, 0, stream>>>(x_new, s_new);
    ln_kernel<<<B_ * LN_, 256, 0, stream>>>(x_new, ln2g, ln2b, nullptr, h2, 0);
    transpose_cast<<<dim3(HID_ / 32, D_ / 32), dim3(32, 8), 0, stream>>>(W1, W1T, D_, HID_);
    gemm_bf16<<<dim3(HID_ / BN, B_ * LN_ / BM, 1), 256, 0, stream>>>(
        h2, W1T, b1, nullptr, nullptr, mid, B_ * LN_, HID_, D_, 3);
    transpose_cast<<<dim3(D_ / 32, HID_ / 32), dim3(32, 8), 0, stream>>>(W2, W2T, HID_, D_);
    // MLP2 GEMM: split-K=4, out preinit with b2 + x_new
    init_out<<<(B_ * LN_ * D_ / 4 + 255) / 256, 256, 0, stream>>>(b2, x_new, out, D_ / 4, B_ * LN_ * D_ / 4);
    gemm_bf16<<<dim3(D_ / BN, B_ * LN_ / BM, 4), 256, 0, stream>>>(
        mid, W2T, b2, nullptr, out, nullptr, B_ * LN_, D_, HID_, 0);
}

// Round 4
// 339.673 us; speedup vs baseline: 2.3667x; 1.0612x over previous
//
#include <hip/hip_runtime.h>
#include <hip/hip_bf16.h>

typedef __attribute__((ext_vector_type(4))) float f32x4;
typedef __attribute__((ext_vector_type(8))) short s16x8;
typedef unsigned short u16;

#define B_   2
#define L_   2048
#define D_   768
#define H_   12
#define HD_  64
#define LN_  1536   // merged length: 512 unm + 1024 dst
#define HID_ 3072

__device__ __forceinline__ u16 f2bf(float f) {
    union { float f; unsigned u; } v; v.f = f;
    unsigned r = (v.u + 0x7FFFu + ((v.u >> 16) & 1u)) >> 16;
    return (u16)r;
}

__device__ __forceinline__ void gload_lds16(const void* g, void* l) {
    __builtin_amdgcn_global_load_lds((const __attribute__((address_space(1))) void*)g,
                                     (__attribute__((address_space(3))) void*)l, 16, 0, 0);
}

// ---------------- LayerNorm (row = 768) ----------------
__global__ __launch_bounds__(256) void ln_kernel(const float* __restrict__ x,
                                                 const float* __restrict__ g,
                                                 const float* __restrict__ bb,
                                                 float* __restrict__ hf,
                                                 u16* __restrict__ hb,
                                                 int storeF32) {
    __shared__ float sm[8];
    int row = blockIdx.x;
    const float* xr = x + (size_t)row * D_;
    int t = threadIdx.x;
    float4 v = make_float4(0.f, 0.f, 0.f, 0.f);
    float s = 0.f, s2 = 0.f;
    if (t < 192) {
        v = ((const float4*)xr)[t];
        s = v.x + v.y + v.z + v.w;
        s2 = v.x * v.x + v.y * v.y + v.z * v.z + v.w * v.w;
    }
    for (int o = 32; o; o >>= 1) { s += __shfl_down(s, o); s2 += __shfl_down(s2, o); }
    int wv = t >> 6, ln = t & 63;
    if (ln == 0) { sm[wv] = s; sm[4 + wv] = s2; }
    __syncthreads();
    if (t == 0) { sm[0] = sm[0] + sm[1] + sm[2] + sm[3]; sm[4] = sm[4] + sm[5] + sm[6] + sm[7]; }
    __syncthreads();
    float mu = sm[0] * (1.f / D_);
    float var = sm[4] * (1.f / D_) - mu * mu;
    float rs = rsqrtf(var + 1e-5f);
    if (t < 192) {
        float4 gg = ((const float4*)g)[t], bv = ((const float4*)bb)[t];
        float4 o;
        o.x = (v.x - mu) * rs * gg.x + bv.x;
        o.y = (v.y - mu) * rs * gg.y + bv.y;
        o.z = (v.z - mu) * rs * gg.z + bv.z;
        o.w = (v.w - mu) * rs * gg.w + bv.w;
        if (storeF32) ((float4*)(hf + (size_t)row * D_))[t] = o;
        ushort4 u;
        u.x = f2bf(o.x); u.y = f2bf(o.y); u.z = f2bf(o.z); u.w = f2bf(o.w);
        ((ushort4*)(hb + (size_t)row * D_))[t] = u;
    }
}

// ---------------- transpose + cast fp32(RxC) -> bf16(CxR) ----------------
__global__ void transpose_cast(const float* __restrict__ in, u16* __restrict__ out, int R, int C) {
    __shared__ float tile[32][33];
    int c0 = blockIdx.x * 32, r0 = blockIdx.y * 32;
    int tx = threadIdx.x, ty = threadIdx.y; // 32 x 8
    for (int i = 0; i < 32; i += 8)
        tile[ty + i][tx] = in[(size_t)(r0 + ty + i) * C + c0 + tx];
    __syncthreads();
    for (int i = 0; i < 32; i += 8)
        out[(size_t)(c0 + ty + i) * R + r0 + tx] = f2bf(tile[tx][ty + i]);
}

// ---------------- init output with bias (+resid) for split-K atomic GEMM ----------------
__global__ __launch_bounds__(256) void init_out(const float* __restrict__ bias,
                                                const float* __restrict__ resid,
                                                float* __restrict__ out, int N4, int total4) {
    int i = blockIdx.x * 256 + threadIdx.x;
    if (i < total4) {
        float4 bv = ((const float4*)bias)[i % N4];
        if (resid) {
            float4 r = ((const float4*)resid)[i];
            bv.x += r.x; bv.y += r.y; bv.z += r.z; bv.w += r.w;
        }
        ((float4*)out)[i] = bv;
    }
}

// ---------------- bf16 MFMA GEMM, 2-phase dbuf pipeline ----------------
// flags: 1=gelu, 2=bf16 out (Cb), 4=qkv-split output (Cb=qk row-major bf16, Vt=v transposed)
#define BM 128
#define BN 128
#define BK 64
__global__ __launch_bounds__(256) void gemm_bf16(const u16* __restrict__ A, const u16* __restrict__ BT,
                                                 const float* __restrict__ bias,
                                                 const float* __restrict__ resid,
                                                 float* __restrict__ Cf, u16* __restrict__ Cb,
                                                 u16* __restrict__ Vt,
                                                 int M, int N, int K, int flags) {
    __shared__ __align__(16) u16 As[2 * BM * BK];
    __shared__ __align__(16) u16 Bs[2 * BM * BK];
    int tid = threadIdx.x;
    int wave = tid >> 6, lane = tid & 63;
    int wr = wave >> 1, wc = wave & 1;
    int mBase = blockIdx.y * BM, nBase = blockIdx.x * BN;
    int l15 = lane & 15, l4 = lane >> 4;
    f32x4 acc[4][4] = {};
    int Ksplit = K / gridDim.z;
    int kt0 = (blockIdx.z * Ksplit) / BK, kt1 = kt0 + Ksplit / BK;
    int lrow = lane >> 3, lsl = lane & 7;

    auto stage = [&](int kt, int buf) {
        size_t koff = (size_t)kt * BK;
        u16* as = &As[buf * BM * BK];
        u16* bs = &Bs[buf * BM * BK];
        #pragma unroll
        for (int i = 0; i < 4; ++i) {
            int rbase = wave * 32 + i * 8;
            int row = rbase + lrow;
            int gc = lsl ^ (row & 7);
            gload_lds16(A + (size_t)(mBase + row) * K + koff + gc * 8, &as[rbase * BK]);
            gload_lds16(BT + (size_t)(nBase + row) * K + koff + gc * 8, &bs[rbase * BK]);
        }
    };

    stage(kt0, 0);
    int cur = 0;
    for (int kt = kt0; kt < kt1; ++kt) {
        if (kt + 1 < kt1) {
            stage(kt + 1, cur ^ 1);
            asm volatile("s_waitcnt vmcnt(8)" ::: "memory");
        } else {
            asm volatile("s_waitcnt vmcnt(0)" ::: "memory");
        }
        __builtin_amdgcn_s_barrier();
        const u16* as = &As[cur * BM * BK];
        const u16* bs = &Bs[cur * BM * BK];
        #pragma unroll
        for (int kk = 0; kk < 2; ++kk) {
            s16x8 af[4], bf[4];
            #pragma unroll
            for (int mi = 0; mi < 4; ++mi) {
                int row = wr * 64 + mi * 16 + l15;
                int ch = kk * 4 + l4;
                af[mi] = *(const s16x8*)(&as[row * BK + (ch ^ (row & 7)) * 8]);
            }
            #pragma unroll
            for (int ni = 0; ni < 4; ++ni) {
                int row = wc * 64 + ni * 16 + l15;
                int ch = kk * 4 + l4;
                bf[ni] = *(const s16x8*)(&bs[row * BK + (ch ^ (row & 7)) * 8]);
            }
            #pragma unroll
            for (int mi = 0; mi < 4; ++mi)
                #pragma unroll
                for (int ni = 0; ni < 4; ++ni)
                    acc[mi][ni] = __builtin_amdgcn_mfma_f32_16x16x32_bf16(af[mi], bf[ni], acc[mi][ni], 0, 0, 0);
        }
        asm volatile("s_waitcnt lgkmcnt(0)" ::: "memory");
        __builtin_amdgcn_s_barrier();
        cur ^= 1;
    }

    if (flags & 4) {
        // QKV split: cols [0,1536) -> Cb row-major (q|k) bf16; cols [1536,2304) -> Vt[b][h][d][tok]
        #pragma unroll
        for (int mi = 0; mi < 4; ++mi) {
            int r0 = mBase + wr * 64 + mi * 16 + l4 * 4;
            #pragma unroll
            for (int ni = 0; ni < 4; ++ni) {
                int c0 = nBase + wc * 64 + ni * 16;
                int col = c0 + l15;
                float bv = bias[col];
                if (c0 < 1536) {
                    #pragma unroll
                    for (int j = 0; j < 4; ++j)
                        Cb[(size_t)(r0 + j) * 1536 + col] = f2bf(acc[mi][ni][j] + bv);
                } else {
                    int hh = (col - 1536) >> 6, dd = (col - 1536) & 63;
                    int bb2 = r0 >> 11, tok = r0 & 2047;
                    ushort4 u;
                    u.x = f2bf(acc[mi][ni][0] + bv);
                    u.y = f2bf(acc[mi][ni][1] + bv);
                    u.z = f2bf(acc[mi][ni][2] + bv);
                    u.w = f2bf(acc[mi][ni][3] + bv);
                    *(ushort4*)&Vt[(((size_t)bb2 * H_ + hh) * HD_ + dd) * (size_t)L_ + tok] = u;
                }
            }
        }
        return;
    }
    if (gridDim.z > 1) {
        #pragma unroll
        for (int mi = 0; mi < 4; ++mi)
            #pragma unroll
            for (int j = 0; j < 4; ++j) {
                int row = mBase + wr * 64 + mi * 16 + l4 * 4 + j;
                #pragma unroll
                for (int ni = 0; ni < 4; ++ni) {
                    int col = nBase + wc * 64 + ni * 16 + l15;
                    unsafeAtomicAdd(&Cf[(size_t)row * N + col], acc[mi][ni][j]);
                }
            }
        return;
    }
    #pragma unroll
    for (int mi = 0; mi < 4; ++mi) {
        #pragma unroll
        for (int j = 0; j < 4; ++j) {
            int row = mBase + wr * 64 + mi * 16 + l4 * 4 + j;
            #pragma unroll
            for (int ni = 0; ni < 4; ++ni) {
                int col = nBase + wc * 64 + ni * 16 + l15;
                float v = acc[mi][ni][j] + bias[col];
                if (resid) v += resid[(size_t)row * N + col];
                if (flags & 1) v = 0.5f * v * (1.f + erff(v * 0.70710678118654752f));
                if (flags & 2) Cb[(size_t)row * N + col] = f2bf(v);
                else Cf[(size_t)row * N + col] = v;
            }
        }
    }
}

// ---------------- build mean-of-head-blocks Wk / bk ----------------
__global__ void build_wkm(const float* __restrict__ Wqkv, const float* __restrict__ bqkv,
                          float* __restrict__ wkm /*[768][64]*/, float* __restrict__ bkm) {
    int idx = blockIdx.x * 256 + threadIdx.x;
    if (idx < D_ * HD_) {
        int k = idx >> 6, c = idx & 63;
        float s = 0.f;
        #pragma unroll
        for (int hh = 0; hh < H_; ++hh) s += Wqkv[(size_t)k * (3 * D_) + D_ + hh * HD_ + c];
        wkm[idx] = s * (1.f / H_);
    }
    if (idx < HD_) {
        float s = 0.f;
        #pragma unroll
        for (int hh = 0; hh < H_; ++hh) s += bqkv[D_ + hh * HD_ + idx];
        bkm[idx] = s * (1.f / H_);
    }
}

// ---------------- k_merge + normalize + even/odd split (fp32) ----------------
__global__ __launch_bounds__(256) void kmerge_kn(const float* __restrict__ hf, const float* __restrict__ wkm,
                                                 const float* __restrict__ bkm,
                                                 float* __restrict__ aset, float* __restrict__ bset) {
    __shared__ float wtile[256 * 64]; // 64KB
    int t = threadIdx.x, wave = t >> 6, lane = t & 63;
    int m0 = blockIdx.x * 16 + wave * 4;
    float acc[4] = {0.f, 0.f, 0.f, 0.f};
    for (int kc = 0; kc < 3; ++kc) {
        __syncthreads();
        for (int i = t; i < 256 * 64 / 4; i += 256)
            ((float4*)wtile)[i] = ((const float4*)(wkm + kc * 256 * 64))[i];
        __syncthreads();
        for (int k = 0; k < 256; ++k) {
            float wv = wtile[k * 64 + lane];
            #pragma unroll
            for (int r = 0; r < 4; ++r)
                acc[r] = fmaf(hf[(size_t)(m0 + r) * D_ + kc * 256 + k], wv, acc[r]);
        }
    }
    #pragma unroll
    for (int r = 0; r < 4; ++r) {
        float v = acc[r] + bkm[lane];
        float n2 = v * v;
        for (int o = 32; o; o >>= 1) n2 += __shfl_xor(n2, o);
        float kn = v / (sqrtf(n2) + 1e-8f);
        int m = m0 + r;
        int bb = m >> 11, l = m & 2047;
        float* dp = (l & 1) ? bset : aset;
        dp[((size_t)bb * 1024 + (l >> 1)) * 64 + lane] = kn;
    }
}

// ---------------- ToMe scores: rowwise max+argmax over 1024 cols ----------------
__global__ __launch_bounds__(256) void tome_scores(const float* __restrict__ aset, const float* __restrict__ bset,
                                                   float* __restrict__ node_max, int* __restrict__ node_idx) {
    __shared__ float aves[4][64];
    __shared__ unsigned long long wmax[4][4];
    int b = blockIdx.y;
    int a0 = blockIdx.x * 4;
    int t = threadIdx.x;
    { int r = t >> 6, d = t & 63; aves[r][d] = aset[((size_t)b * 1024 + a0 + r) * 64 + d]; }
    __syncthreads();
    unsigned long long best[4] = {0ull, 0ull, 0ull, 0ull};
    for (int c = t; c < 1024; c += 256) {
        const float4* brow = (const float4*)(bset + ((size_t)b * 1024 + c) * 64);
        float dot[4] = {0.f, 0.f, 0.f, 0.f};
        #pragma unroll
        for (int i = 0; i < 16; ++i) {
            float4 bv = brow[i];
            #pragma unroll
            for (int r = 0; r < 4; ++r) {
                dot[r] = fmaf(aves[r][4 * i + 0], bv.x, dot[r]);
                dot[r] = fmaf(aves[r][4 * i + 1], bv.y, dot[r]);
                dot[r] = fmaf(aves[r][4 * i + 2], bv.z, dot[r]);
                dot[r] = fmaf(aves[r][4 * i + 3], bv.w, dot[r]);
            }
        }
        #pragma unroll
        for (int r = 0; r < 4; ++r) {
            unsigned bits = __float_as_uint(dot[r]);
            unsigned u = (bits & 0x80000000u) ? ~bits : (bits | 0x80000000u);
            unsigned long long key = ((unsigned long long)u << 32) | (unsigned)(0xFFFFFFFFu - (unsigned)c);
            best[r] = best[r] > key ? best[r] : key;
        }
    }
    int wv = t >> 6, ln = t & 63;
    #pragma unroll
    for (int r = 0; r < 4; ++r) {
        unsigned long long v = best[r];
        for (int o = 32; o; o >>= 1) {
            unsigned long long w = __shfl_xor(v, o);
            v = v > w ? v : w;
        }
        if (ln == 0) wmax[r][wv] = v;
    }
    __syncthreads();
    if (t == 0) {
        for (int r = 0; r < 4; ++r) {
            int a = a0 + r;
            unsigned long long m = wmax[r][0];
            for (int w = 1; w < 4; ++w) m = m > wmax[r][w] ? m : wmax[r][w];
            float val; int idx;
            if (a == 0) { val = -INFINITY; idx = 0; }
            else {
                unsigned u = (unsigned)(m >> 32);
                unsigned bits = (u & 0x80000000u) ? (u ^ 0x80000000u) : ~u;
                val = __uint_as_float(bits);
                idx = (int)(0xFFFFFFFFu - (unsigned)(m & 0xFFFFFFFFu));
            }
            node_max[b * 1024 + a] = val;
            node_idx[b * 1024 + a] = idx;
        }
    }
}

// ---------------- stable argsort (desc value, asc idx) + unm sort ----------------
__global__ __launch_bounds__(512) void tome_sort(const float* __restrict__ node_max, const int* __restrict__ node_idx,
                                                 int* __restrict__ src_idx, int* __restrict__ dst_idx,
                                                 int* __restrict__ unm_idx) {
    __shared__ unsigned long long keys[1024];
    __shared__ int idxs[512];
    int b = blockIdx.x, t = threadIdx.x;
    for (int i = t; i < 1024; i += 512) {
        float v = node_max[b * 1024 + i];
        unsigned bits = __float_as_uint(v);
        unsigned u = (bits & 0x80000000u) ? ~bits : (bits | 0x80000000u);
        keys[i] = ((unsigned long long)(~u) << 32) | (unsigned)i; // ascending == desc value, asc idx
    }
    __syncthreads();
    for (int k = 2; k <= 1024; k <<= 1)
        for (int j = k >> 1; j > 0; j >>= 1) {
            for (int i = t; i < 1024; i += 512) {
                int ixj = i ^ j;
                if (ixj > i) {
                    bool up = (i & k) == 0;
                    unsigned long long a = keys[i], c = keys[ixj];
                    if (up ? (a > c) : (a < c)) { keys[i] = c; keys[ixj] = a; }
                }
            }
            __syncthreads();
        }
    {
        int s = (int)(keys[t] & 0xFFFFFFFFu);
        src_idx[b * 512 + t] = s;
        dst_idx[b * 512 + t] = node_idx[b * 1024 + s];
        idxs[t] = (int)(keys[512 + t] & 0xFFFFFFFFu);
    }
    __syncthreads();
    for (int k = 2; k <= 512; k <<= 1)
        for (int j = k >> 1; j > 0; j >>= 1) {
            int i = t, ixj = t ^ j;
            if (ixj > i) {
                bool up = (i & k) == 0;
                int a = idxs[i], c = idxs[ixj];
                if (up ? (a > c) : (a < c)) { idxs[i] = c; idxs[ixj] = a; }
            }
            __syncthreads();
        }
    unm_idx[b * 512 + t] = idxs[t];
}

// ---------------- windowed attention via MFMA (bf16 inputs) ----------------
__global__ __launch_bounds__(256) void attn_mfma(const u16* __restrict__ qkb,
                                                 const u16* __restrict__ vtb,
                                                 const float* __restrict__ ts,
                                                 u16* __restrict__ ctx) {
    __shared__ __align__(16) u16 Ks[160 * 64];      // XOR-swizzled [key][dim]
    __shared__ __align__(16) u16 Vt[64][168];       // [dim][key] pad->168
    __shared__ float lts[160];
    __shared__ __align__(16) u16 Pw[4][16 * 40];    // per-wave P round-trip, stride 40
    int qt = blockIdx.x, h = blockIdx.y, b = blockIdx.z;
    int tid = threadIdx.x, wave = tid >> 6, lane = tid & 63;
    int l15 = lane & 15, l4 = lane >> 4;
    int qbase = qt * 64 + wave * 16;
    int jbase0 = qt * 64 - 128;

    s16x8 qaf[2];
    {
        const u16* qp = qkb + (size_t)(b * L_ + qbase + l15) * 1536 + h * HD_;
        qaf[0] = *(const s16x8*)(qp + l4 * 8);
        qaf[1] = *(const s16x8*)(qp + 32 + l4 * 8);
    }
    f32x4 oacc[4] = {};
    float sums[4] = {0.f, 0.f, 0.f, 0.f};
    const u16* vbase = vtb + (size_t)(b * H_ + h) * HD_ * L_;

    for (int half = 0; half < 2; ++half) {
        int jbase = jbase0 + half * 160;
        __syncthreads();
        // K: async global->LDS (linear dest, pre-swizzled source)
        #pragma unroll
        for (int i = 0; i < 5; ++i) {
            int rbase = (wave * 5 + i) * 8;
            int row = rbase + (lane >> 3);
            int gc = (lane & 7) ^ (row & 7);
            int jc = min(max(jbase + row, 0), L_ - 1);
            gload_lds16(qkb + (size_t)(b * L_ + jc) * 1536 + 768 + h * HD_ + gc * 8, &Ks[rbase * 64]);
        }
        // V: coalesced bf16 rows from vtb -> padded Vt
        #pragma unroll
        for (int i = 0; i < 5; ++i) {
            int c = tid + 256 * i;          // 0..1279
            int d = c / 20, ch = c % 20;
            int tok0 = min(max(jbase + ch * 8, 0), L_ - 8);
            s16x8 v = *(const s16x8*)(vbase + (size_t)d * L_ + tok0);
            *(s16x8*)&Vt[d][ch * 8] = v;
        }
        if (tid < 160) {
            int jc = min(max(jbase + tid, 0), L_ - 1);
            lts[tid] = __logf(fmaxf(ts[b * L_ + jc], 1e-8f));
        }
        __syncthreads();
        #pragma unroll
        for (int kb = 0; kb < 5; ++kb) {
            #pragma unroll
            for (int f = 0; f < 2; ++f) {
                int kf16 = kb * 32 + f * 16;
                f32x4 s = {};
                #pragma unroll
                for (int c = 0; c < 2; ++c) {
                    int row = kf16 + l15;
                    int ch = (c * 4 + l4) ^ (row & 7);
                    s16x8 kf = *(const s16x8*)&Ks[row * 64 + ch * 8];
                    s = __builtin_amdgcn_mfma_f32_16x16x32_bf16(qaf[c], kf, s, 0, 0, 0);
                }
                int j = jbase + kf16 + l15;
                float lt = lts[kf16 + l15];
                #pragma unroll
                for (int jj = 0; jj < 4; ++jj) {
                    int q = qbase + l4 * 4 + jj;
                    int d = j - q;
                    bool ok = (j >= 0) && (j < L_) && (d >= -128) && (d <= 128);
                    float p = ok ? __expf(s[jj] * 0.125f + lt) : 0.f;
                    sums[jj] += p;
                    Pw[wave][(l4 * 4 + jj) * 40 + f * 16 + l15] = f2bf(p);
                }
            }
            asm volatile("s_waitcnt lgkmcnt(0)" ::: "memory");
            s16x8 paf = *(const s16x8*)&Pw[wave][l15 * 40 + l4 * 8];
            #pragma unroll
            for (int df = 0; df < 4; ++df) {
                s16x8 vbf = *(const s16x8*)&Vt[df * 16 + l15][kb * 32 + l4 * 8];
                oacc[df] = __builtin_amdgcn_mfma_f32_16x16x32_bf16(paf, vbf, oacc[df], 0, 0, 0);
            }
        }
    }
    #pragma unroll
    for (int jj = 0; jj < 4; ++jj) {
        float s = sums[jj];
        s += __shfl_xor(s, 1); s += __shfl_xor(s, 2);
        s += __shfl_xor(s, 4); s += __shfl_xor(s, 8);
        sums[jj] = 1.f / s;
    }
    #pragma unroll
    for (int jj = 0; jj < 4; ++jj) {
        int q = qbase + l4 * 4 + jj;
        u16* crow = ctx + (size_t)(b * L_ + q) * D_ + h * HD_;
        #pragma unroll
        for (int df = 0; df < 4; ++df)
            crow[df * 16 + l15] = f2bf(oacc[df][jj] * sums[jj]);
    }
}

// ---------------- merge kernels ----------------
__global__ __launch_bounds__(256) void merge_init(const float* __restrict__ xm, const float* __restrict__ ts,
                                                  const int* __restrict__ unm_idx,
                                                  float* __restrict__ x_sum, float* __restrict__ s_new) {
    int row = blockIdx.x;
    int b = row / LN_, rl = row % LN_;
    int srcTok = (rl < 512) ? (2 * unm_idx[b * 512 + rl]) : (2 * (rl - 512) + 1);
    float tsv = ts[b * L_ + srcTok];
    const float* src = xm + (size_t)(b * L_ + srcTok) * D_;
    float* dst = x_sum + (size_t)(b * LN_ + rl) * D_;
    int t = threadIdx.x;
    if (t < 192) {
        float4 v = ((const float4*)src)[t];
        v.x *= tsv; v.y *= tsv; v.z *= tsv; v.w *= tsv;
        ((float4*)dst)[t] = v;
    }
    if (t == 0) s_new[b * LN_ + rl] = tsv;
}

__global__ __launch_bounds__(256) void merge_scatter(const float* __restrict__ xm, const float* __restrict__ ts,
                                                     const int* __restrict__ src_idx, const int* __restrict__ dst_idx,
                                                     float* __restrict__ x_sum, float* __restrict__ s_new) {
    int e = blockIdx.x;
    int b = e >> 9, el = e & 511;
    int s = src_idx[b * 512 + el];
    int dtok = dst_idx[b * 512 + el];
    int srcTok = 2 * s;
    float tsv = ts[b * L_ + srcTok];
    const float* src = xm + (size_t)(b * L_ + srcTok) * D_;
    float* dst = x_sum + (size_t)(b * LN_ + 512 + dtok) * D_;
    for (int i = threadIdx.x; i < D_; i += 256) atomicAdd(&dst[i], src[i] * tsv);
    if (threadIdx.x == 0) atomicAdd(&s_new[b * LN_ + 512 + dtok], tsv);
}

__global__ __launch_bounds__(256) void merge_div(float* __restrict__ x_sum, const float* __restrict__ s_new) {
    int row = blockIdx.x;
    float inv = 1.f / (s_new[row] + 1e-8f);
    float* p = x_sum + (size_t)row * D_;
    int t = threadIdx.x;
    if (t < 192) {
        float4 v = ((float4*)p)[t];
        v.x *= inv; v.y *= inv; v.z *= inv; v.w *= inv;
        ((float4*)p)[t] = v;
    }
}

extern "C" void kernel_launch(void* const* d_in, const int* in_sizes, int n_in,
                              void* d_out, int out_size, void* d_ws, size_t ws_size,
                              hipStream_t stream) {
    (void)in_sizes; (void)n_in; (void)out_size; (void)ws_size;
    const float* x     = (const float*)d_in[0];
    const float* ts    = (const float*)d_in[1];
    const float* ln1g  = (const float*)d_in[2];
    const float* ln1b  = (const float*)d_in[3];
    const float* ln2g  = (const float*)d_in[4];
    const float* ln2b  = (const float*)d_in[5];
    const float* Wqkv  = (const float*)d_in[6];
    const float* bqkv  = (const float*)d_in[7];
    const float* Wproj = (const float*)d_in[8];
    const float* bproj = (const float*)d_in[9];
    const float* W1    = (const float*)d_in[10];
    const float* b1    = (const float*)d_in[11];
    const float* W2    = (const float*)d_in[12];
    const float* b2    = (const float*)d_in[13];
    float* out = (float*)d_out;

    char* ws = (char*)d_ws;
    float* h_f32   = (float*)(ws + 0);            // 12582912  (reused as xm)
    u16*   h_bf16  = (u16*)(ws + 12582912);       // 6291456   (reused as ctx)
    u16*   qkb     = (u16*)(ws + 18874368);       // 12582912  [4096][1536] bf16
    u16*   vtb     = (u16*)(ws + 31457280);       // 6291456   [2][12][64][2048] bf16
    u16*   mid     = (u16*)(ws + 37748736);       // 18874368  [3072][3072] bf16
    float* x_new   = (float*)(ws + 56623104);     // 9437184
    float* s_new   = (float*)(ws + 66060288);     // 12288
    u16*   h2      = (u16*)(ws + 66072576);       // 4718592
    u16*   WqkvT   = (u16*)(ws + 70791168);       // 3538944
    u16*   WprojT  = (u16*)(ws + 74330112);       // 1179648
    u16*   W1T     = (u16*)(ws + 75509760);       // 4718592
    u16*   W2T     = (u16*)(ws + 80228352);       // 4718592
    float* wkm     = (float*)(ws + 84946944);     // 196608
    float* bkm     = (float*)(ws + 85143552);     // 256
    float* aset    = (float*)(ws + 85143808);     // 524288
    float* bset    = (float*)(ws + 85668096);     // 524288
    float* nmax    = (float*)(ws + 86192384);     // 8192
    int*   nidx    = (int*)(ws + 86200576);       // 8192
    int*   src_idx = (int*)(ws + 86208768);       // 4096
    int*   dst_idx = (int*)(ws + 86212864);       // 4096
    int*   unm_idx = (int*)(ws + 86216960);       // 4096
    float* xm  = h_f32;
    u16*   ctx = h_bf16;

    ln_kernel<<<B_ * L_, 256, 0, stream>>>(x, ln1g, ln1b, h_f32, h_bf16, 1);
    build_wkm<<<192, 256, 0, stream>>>(Wqkv, bqkv, wkm, bkm);
    transpose_cast<<<dim3(3 * D_ / 32, D_ / 32), dim3(32, 8), 0, stream>>>(Wqkv, WqkvT, D_, 3 * D_);
    // QKV GEMM -> qk bf16 row-major + V transposed
    gemm_bf16<<<dim3(3 * D_ / BN, B_ * L_ / BM, 1), 256, 0, stream>>>(
        h_bf16, WqkvT, bqkv, nullptr, nullptr, qkb, vtb, B_ * L_, 3 * D_, D_, 4);
    kmerge_kn<<<B_ * L_ / 16, 256, 0, stream>>>(h_f32, wkm, bkm, aset, bset);
    tome_scores<<<dim3(256, B_), 256, 0, stream>>>(aset, bset, nmax, nidx);
    tome_sort<<<B_, 512, 0, stream>>>(nmax, nidx, src_idx, dst_idx, unm_idx);
    attn_mfma<<<dim3(L_ / 64, H_, B_), 256, 0, stream>>>(qkb, vtb, ts, ctx);
    transpose_cast<<<dim3(D_ / 32, D_ / 32), dim3(32, 8), 0, stream>>>(Wproj, WprojT, D_, D_);
    // proj GEMM: split-K=2, out preinit with bproj + x
    init_out<<<(B_ * L_ * D_ / 4 + 255) / 256, 256, 0, stream>>>(bproj, x, xm, D_ / 4, B_ * L_ * D_ / 4);
    gemm_bf16<<<dim3(D_ / BN, B_ * L_ / BM, 2), 256, 0, stream>>>(
        ctx, WprojT, bproj, nullptr, xm, nullptr, nullptr, B_ * L_, D_, D_, 0);
    merge_init<<<B_ * LN_, 256, 0, stream>>>(xm, ts, unm_idx, x_new, s_new);
    merge_scatter<<<B_ * 512, 256, 0, stream>>>(xm, ts, src_idx, dst_idx, x_new, s_new);
    merge_div<<<B_ * LN_, 256, 0, stream>>>(x_new, s_new);
    ln_kernel<<<B_ * LN_, 256, 0, stream>>>(x_new, ln2g, ln2b, nullptr, h2, 0);
    transpose_cast<<<dim3(HID_ / 32, D_ / 32), dim3(32, 8), 0, stream>>>(W1, W1T, D_, HID_);
    gemm_bf16<<<dim3(HID_ / BN, B_ * LN_ / BM, 1), 256, 0, stream>>>(
        h2, W1T, b1, nullptr, nullptr, mid, nullptr, B_ * LN_, HID_, D_, 3);
    transpose_cast<<<dim3(D_ / 32, HID_ / 32), dim3(32, 8), 0, stream>>>(W2, W2T, HID_, D_);
    // MLP2 GEMM: split-K=4, out preinit with b2 + x_new
    init_out<<<(B_ * LN_ * D_ / 4 + 255) / 256, 256, 0, stream>>>(b2, x_new, out, D_ / 4, B_ * LN_ * D_ / 4);
    gemm_bf16<<<dim3(D_ / BN, B_ * LN_ / BM, 4), 256, 0, stream>>>(
        mid, W2T, b2, nullptr, out, nullptr, nullptr, B_ * LN_, D_, HID_, 0);
}

// Round 5
// 322.911 us; speedup vs baseline: 2.4895x; 1.0519x over previous
//
#include <hip/hip_runtime.h>
#include <hip/hip_bf16.h>

typedef __attribute__((ext_vector_type(4))) float f32x4;
typedef __attribute__((ext_vector_type(8))) short s16x8;
typedef unsigned short u16;

#define B_   2
#define L_   2048
#define D_   768
#define H_   12
#define HD_  64
#define LN_  1536   // merged length: 512 unm + 1024 dst
#define HID_ 3072

__device__ __forceinline__ u16 f2bf(float f) {
    union { float f; unsigned u; } v; v.f = f;
    unsigned r = (v.u + 0x7FFFu + ((v.u >> 16) & 1u)) >> 16;
    return (u16)r;
}

__device__ __forceinline__ void gload_lds16(const void* g, void* l) {
    __builtin_amdgcn_global_load_lds((const __attribute__((address_space(1))) void*)g,
                                     (__attribute__((address_space(3))) void*)l, 16, 0, 0);
}

// ---------------- LayerNorm (row = 768) ----------------
__global__ __launch_bounds__(256) void ln_kernel(const float* __restrict__ x,
                                                 const float* __restrict__ g,
                                                 const float* __restrict__ bb,
                                                 float* __restrict__ hf,
                                                 u16* __restrict__ hb,
                                                 int storeF32) {
    __shared__ float sm[8];
    int row = blockIdx.x;
    const float* xr = x + (size_t)row * D_;
    int t = threadIdx.x;
    float4 v = make_float4(0.f, 0.f, 0.f, 0.f);
    float s = 0.f, s2 = 0.f;
    if (t < 192) {
        v = ((const float4*)xr)[t];
        s = v.x + v.y + v.z + v.w;
        s2 = v.x * v.x + v.y * v.y + v.z * v.z + v.w * v.w;
    }
    for (int o = 32; o; o >>= 1) { s += __shfl_down(s, o); s2 += __shfl_down(s2, o); }
    int wv = t >> 6, ln = t & 63;
    if (ln == 0) { sm[wv] = s; sm[4 + wv] = s2; }
    __syncthreads();
    if (t == 0) { sm[0] = sm[0] + sm[1] + sm[2] + sm[3]; sm[4] = sm[4] + sm[5] + sm[6] + sm[7]; }
    __syncthreads();
    float mu = sm[0] * (1.f / D_);
    float var = sm[4] * (1.f / D_) - mu * mu;
    float rs = rsqrtf(var + 1e-5f);
    if (t < 192) {
        float4 gg = ((const float4*)g)[t], bv = ((const float4*)bb)[t];
        float4 o;
        o.x = (v.x - mu) * rs * gg.x + bv.x;
        o.y = (v.y - mu) * rs * gg.y + bv.y;
        o.z = (v.z - mu) * rs * gg.z + bv.z;
        o.w = (v.w - mu) * rs * gg.w + bv.w;
        if (storeF32) ((float4*)(hf + (size_t)row * D_))[t] = o;
        ushort4 u;
        u.x = f2bf(o.x); u.y = f2bf(o.y); u.z = f2bf(o.z); u.w = f2bf(o.w);
        ((ushort4*)(hb + (size_t)row * D_))[t] = u;
    }
}

// ---------------- transpose + cast fp32(RxC) -> bf16(CxR) ----------------
__global__ void transpose_cast(const float* __restrict__ in, u16* __restrict__ out, int R, int C) {
    __shared__ float tile[32][33];
    int c0 = blockIdx.x * 32, r0 = blockIdx.y * 32;
    int tx = threadIdx.x, ty = threadIdx.y; // 32 x 8
    for (int i = 0; i < 32; i += 8)
        tile[ty + i][tx] = in[(size_t)(r0 + ty + i) * C + c0 + tx];
    __syncthreads();
    for (int i = 0; i < 32; i += 8)
        out[(size_t)(c0 + ty + i) * R + r0 + tx] = f2bf(tile[tx][ty + i]);
}

// ---------------- split-K partial reduce: out = sum(parts) + bias + resid ----------------
__global__ __launch_bounds__(256) void reduce_splitk(const float* __restrict__ parts,
                                                     const float* __restrict__ bias,
                                                     const float* __restrict__ resid,
                                                     float* __restrict__ out,
                                                     int nparts, int MN4, int N4, int total4) {
    int i = blockIdx.x * 256 + threadIdx.x;
    if (i >= total4) return;
    float4 s = ((const float4*)parts)[i];
    for (int p = 1; p < nparts; ++p) {
        float4 v = ((const float4*)parts)[(size_t)p * MN4 + i];
        s.x += v.x; s.y += v.y; s.z += v.z; s.w += v.w;
    }
    float4 bv = ((const float4*)bias)[i % N4];
    s.x += bv.x; s.y += bv.y; s.z += bv.z; s.w += bv.w;
    if (resid) {
        float4 r = ((const float4*)resid)[i];
        s.x += r.x; s.y += r.y; s.z += r.z; s.w += r.w;
    }
    ((float4*)out)[i] = s;
}

// ---------------- bf16 MFMA GEMM, 2-phase dbuf pipeline ----------------
// flags: 1=gelu, 2=bf16 out (Cb), 4=qkv-split output (Cb=qk row-major bf16, Vt=v transposed)
// gridDim.z>1: store partial tile (no bias/resid) to Cf + z*M*N with regular stores.
#define BM 128
#define BN 128
#define BK 64
__global__ __launch_bounds__(256) void gemm_bf16(const u16* __restrict__ A, const u16* __restrict__ BT,
                                                 const float* __restrict__ bias,
                                                 const float* __restrict__ resid,
                                                 float* __restrict__ Cf, u16* __restrict__ Cb,
                                                 u16* __restrict__ Vt,
                                                 int M, int N, int K, int flags) {
    __shared__ __align__(16) u16 As[2 * BM * BK];
    __shared__ __align__(16) u16 Bs[2 * BM * BK];
    int tid = threadIdx.x;
    int wave = tid >> 6, lane = tid & 63;
    int wr = wave >> 1, wc = wave & 1;
    int mBase = blockIdx.y * BM, nBase = blockIdx.x * BN;
    int l15 = lane & 15, l4 = lane >> 4;
    f32x4 acc[4][4] = {};
    int Ksplit = K / gridDim.z;
    int kt0 = (blockIdx.z * Ksplit) / BK, kt1 = kt0 + Ksplit / BK;
    int lrow = lane >> 3, lsl = lane & 7;

    auto stage = [&](int kt, int buf) {
        size_t koff = (size_t)kt * BK;
        u16* as = &As[buf * BM * BK];
        u16* bs = &Bs[buf * BM * BK];
        #pragma unroll
        for (int i = 0; i < 4; ++i) {
            int rbase = wave * 32 + i * 8;
            int row = rbase + lrow;
            int gc = lsl ^ (row & 7);
            gload_lds16(A + (size_t)(mBase + row) * K + koff + gc * 8, &as[rbase * BK]);
            gload_lds16(BT + (size_t)(nBase + row) * K + koff + gc * 8, &bs[rbase * BK]);
        }
    };

    stage(kt0, 0);
    int cur = 0;
    for (int kt = kt0; kt < kt1; ++kt) {
        if (kt + 1 < kt1) {
            stage(kt + 1, cur ^ 1);
            asm volatile("s_waitcnt vmcnt(8)" ::: "memory");
        } else {
            asm volatile("s_waitcnt vmcnt(0)" ::: "memory");
        }
        __builtin_amdgcn_s_barrier();
        const u16* as = &As[cur * BM * BK];
        const u16* bs = &Bs[cur * BM * BK];
        #pragma unroll
        for (int kk = 0; kk < 2; ++kk) {
            s16x8 af[4], bf[4];
            #pragma unroll
            for (int mi = 0; mi < 4; ++mi) {
                int row = wr * 64 + mi * 16 + l15;
                int ch = kk * 4 + l4;
                af[mi] = *(const s16x8*)(&as[row * BK + (ch ^ (row & 7)) * 8]);
            }
            #pragma unroll
            for (int ni = 0; ni < 4; ++ni) {
                int row = wc * 64 + ni * 16 + l15;
                int ch = kk * 4 + l4;
                bf[ni] = *(const s16x8*)(&bs[row * BK + (ch ^ (row & 7)) * 8]);
            }
            #pragma unroll
            for (int mi = 0; mi < 4; ++mi)
                #pragma unroll
                for (int ni = 0; ni < 4; ++ni)
                    acc[mi][ni] = __builtin_amdgcn_mfma_f32_16x16x32_bf16(af[mi], bf[ni], acc[mi][ni], 0, 0, 0);
        }
        asm volatile("s_waitcnt lgkmcnt(0)" ::: "memory");
        __builtin_amdgcn_s_barrier();
        cur ^= 1;
    }

    if (flags & 4) {
        // QKV split: cols [0,1536) -> Cb row-major (q|k) bf16; cols [1536,2304) -> Vt[b][h][d][tok]
        #pragma unroll
        for (int mi = 0; mi < 4; ++mi) {
            int r0 = mBase + wr * 64 + mi * 16 + l4 * 4;
            #pragma unroll
            for (int ni = 0; ni < 4; ++ni) {
                int c0 = nBase + wc * 64 + ni * 16;
                int col = c0 + l15;
                float bv = bias[col];
                if (c0 < 1536) {
                    #pragma unroll
                    for (int j = 0; j < 4; ++j)
                        Cb[(size_t)(r0 + j) * 1536 + col] = f2bf(acc[mi][ni][j] + bv);
                } else {
                    int hh = (col - 1536) >> 6, dd = (col - 1536) & 63;
                    int bb2 = r0 >> 11, tok = r0 & 2047;
                    ushort4 u;
                    u.x = f2bf(acc[mi][ni][0] + bv);
                    u.y = f2bf(acc[mi][ni][1] + bv);
                    u.z = f2bf(acc[mi][ni][2] + bv);
                    u.w = f2bf(acc[mi][ni][3] + bv);
                    *(ushort4*)&Vt[(((size_t)bb2 * H_ + hh) * HD_ + dd) * (size_t)L_ + tok] = u;
                }
            }
        }
        return;
    }
    if (gridDim.z > 1) {
        // split-K: store partial tile (regular stores, no atomics)
        float* dst = Cf + (size_t)blockIdx.z * M * N;
        #pragma unroll
        for (int mi = 0; mi < 4; ++mi)
            #pragma unroll
            for (int j = 0; j < 4; ++j) {
                int row = mBase + wr * 64 + mi * 16 + l4 * 4 + j;
                #pragma unroll
                for (int ni = 0; ni < 4; ++ni) {
                    int col = nBase + wc * 64 + ni * 16 + l15;
                    dst[(size_t)row * N + col] = acc[mi][ni][j];
                }
            }
        return;
    }
    #pragma unroll
    for (int mi = 0; mi < 4; ++mi) {
        #pragma unroll
        for (int j = 0; j < 4; ++j) {
            int row = mBase + wr * 64 + mi * 16 + l4 * 4 + j;
            #pragma unroll
            for (int ni = 0; ni < 4; ++ni) {
                int col = nBase + wc * 64 + ni * 16 + l15;
                float v = acc[mi][ni][j] + bias[col];
                if (resid) v += resid[(size_t)row * N + col];
                if (flags & 1) v = 0.5f * v * (1.f + erff(v * 0.70710678118654752f));
                if (flags & 2) Cb[(size_t)row * N + col] = f2bf(v);
                else Cf[(size_t)row * N + col] = v;
            }
        }
    }
}

// ---------------- build mean-of-head-blocks Wk / bk ----------------
__global__ void build_wkm(const float* __restrict__ Wqkv, const float* __restrict__ bqkv,
                          float* __restrict__ wkm /*[768][64]*/, float* __restrict__ bkm) {
    int idx = blockIdx.x * 256 + threadIdx.x;
    if (idx < D_ * HD_) {
        int k = idx >> 6, c = idx & 63;
        float s = 0.f;
        #pragma unroll
        for (int hh = 0; hh < H_; ++hh) s += Wqkv[(size_t)k * (3 * D_) + D_ + hh * HD_ + c];
        wkm[idx] = s * (1.f / H_);
    }
    if (idx < HD_) {
        float s = 0.f;
        #pragma unroll
        for (int hh = 0; hh < H_; ++hh) s += bqkv[D_ + hh * HD_ + idx];
        bkm[idx] = s * (1.f / H_);
    }
}

// ---------------- k_merge + normalize + even/odd split (fp32) ----------------
__global__ __launch_bounds__(256) void kmerge_kn(const float* __restrict__ hf, const float* __restrict__ wkm,
                                                 const float* __restrict__ bkm,
                                                 float* __restrict__ aset, float* __restrict__ bset) {
    __shared__ float wtile[256 * 64]; // 64KB
    int t = threadIdx.x, wave = t >> 6, lane = t & 63;
    int m0 = blockIdx.x * 16 + wave * 4;
    float acc[4] = {0.f, 0.f, 0.f, 0.f};
    for (int kc = 0; kc < 3; ++kc) {
        __syncthreads();
        for (int i = t; i < 256 * 64 / 4; i += 256)
            ((float4*)wtile)[i] = ((const float4*)(wkm + kc * 256 * 64))[i];
        __syncthreads();
        for (int k = 0; k < 256; ++k) {
            float wv = wtile[k * 64 + lane];
            #pragma unroll
            for (int r = 0; r < 4; ++r)
                acc[r] = fmaf(hf[(size_t)(m0 + r) * D_ + kc * 256 + k], wv, acc[r]);
        }
    }
    #pragma unroll
    for (int r = 0; r < 4; ++r) {
        float v = acc[r] + bkm[lane];
        float n2 = v * v;
        for (int o = 32; o; o >>= 1) n2 += __shfl_xor(n2, o);
        float kn = v / (sqrtf(n2) + 1e-8f);
        int m = m0 + r;
        int bb = m >> 11, l = m & 2047;
        float* dp = (l & 1) ? bset : aset;
        dp[((size_t)bb * 1024 + (l >> 1)) * 64 + lane] = kn;
    }
}

// ---------------- ToMe scores: rowwise max+argmax over 1024 cols ----------------
__global__ __launch_bounds__(256) void tome_scores(const float* __restrict__ aset, const float* __restrict__ bset,
                                                   float* __restrict__ node_max, int* __restrict__ node_idx) {
    __shared__ float aves[4][64];
    __shared__ unsigned long long wmax[4][4];
    int b = blockIdx.y;
    int a0 = blockIdx.x * 4;
    int t = threadIdx.x;
    { int r = t >> 6, d = t & 63; aves[r][d] = aset[((size_t)b * 1024 + a0 + r) * 64 + d]; }
    __syncthreads();
    unsigned long long best[4] = {0ull, 0ull, 0ull, 0ull};
    for (int c = t; c < 1024; c += 256) {
        const float4* brow = (const float4*)(bset + ((size_t)b * 1024 + c) * 64);
        float dot[4] = {0.f, 0.f, 0.f, 0.f};
        #pragma unroll
        for (int i = 0; i < 16; ++i) {
            float4 bv = brow[i];
            #pragma unroll
            for (int r = 0; r < 4; ++r) {
                dot[r] = fmaf(aves[r][4 * i + 0], bv.x, dot[r]);
                dot[r] = fmaf(aves[r][4 * i + 1], bv.y, dot[r]);
                dot[r] = fmaf(aves[r][4 * i + 2], bv.z, dot[r]);
                dot[r] = fmaf(aves[r][4 * i + 3], bv.w, dot[r]);
            }
        }
        #pragma unroll
        for (int r = 0; r < 4; ++r) {
            unsigned bits = __float_as_uint(dot[r]);
            unsigned u = (bits & 0x80000000u) ? ~bits : (bits | 0x80000000u);
            unsigned long long key = ((unsigned long long)u << 32) | (unsigned)(0xFFFFFFFFu - (unsigned)c);
            best[r] = best[r] > key ? best[r] : key;
        }
    }
    int wv = t >> 6, ln = t & 63;
    #pragma unroll
    for (int r = 0; r < 4; ++r) {
        unsigned long long v = best[r];
        for (int o = 32; o; o >>= 1) {
            unsigned long long w = __shfl_xor(v, o);
            v = v > w ? v : w;
        }
        if (ln == 0) wmax[r][wv] = v;
    }
    __syncthreads();
    if (t == 0) {
        for (int r = 0; r < 4; ++r) {
            int a = a0 + r;
            unsigned long long m = wmax[r][0];
            for (int w = 1; w < 4; ++w) m = m > wmax[r][w] ? m : wmax[r][w];
            float val; int idx;
            if (a == 0) { val = -INFINITY; idx = 0; }
            else {
                unsigned u = (unsigned)(m >> 32);
                unsigned bits = (u & 0x80000000u) ? (u ^ 0x80000000u) : ~u;
                val = __uint_as_float(bits);
                idx = (int)(0xFFFFFFFFu - (unsigned)(m & 0xFFFFFFFFu));
            }
            node_max[b * 1024 + a] = val;
            node_idx[b * 1024 + a] = idx;
        }
    }
}

// ---------------- stable argsort (desc value, asc idx) + unm sort ----------------
__global__ __launch_bounds__(512) void tome_sort(const float* __restrict__ node_max, const int* __restrict__ node_idx,
                                                 int* __restrict__ src_idx, int* __restrict__ dst_idx,
                                                 int* __restrict__ unm_idx) {
    __shared__ unsigned long long keys[1024];
    __shared__ int idxs[512];
    int b = blockIdx.x, t = threadIdx.x;
    for (int i = t; i < 1024; i += 512) {
        float v = node_max[b * 1024 + i];
        unsigned bits = __float_as_uint(v);
        unsigned u = (bits & 0x80000000u) ? ~bits : (bits | 0x80000000u);
        keys[i] = ((unsigned long long)(~u) << 32) | (unsigned)i; // ascending == desc value, asc idx
    }
    __syncthreads();
    for (int k = 2; k <= 1024; k <<= 1)
        for (int j = k >> 1; j > 0; j >>= 1) {
            for (int i = t; i < 1024; i += 512) {
                int ixj = i ^ j;
                if (ixj > i) {
                    bool up = (i & k) == 0;
                    unsigned long long a = keys[i], c = keys[ixj];
                    if (up ? (a > c) : (a < c)) { keys[i] = c; keys[ixj] = a; }
                }
            }
            __syncthreads();
        }
    {
        int s = (int)(keys[t] & 0xFFFFFFFFu);
        src_idx[b * 512 + t] = s;
        dst_idx[b * 512 + t] = node_idx[b * 1024 + s];
        idxs[t] = (int)(keys[512 + t] & 0xFFFFFFFFu);
    }
    __syncthreads();
    for (int k = 2; k <= 512; k <<= 1)
        for (int j = k >> 1; j > 0; j >>= 1) {
            int i = t, ixj = t ^ j;
            if (ixj > i) {
                bool up = (i & k) == 0;
                int a = idxs[i], c = idxs[ixj];
                if (up ? (a > c) : (a < c)) { idxs[i] = c; idxs[ixj] = a; }
            }
            __syncthreads();
        }
    unm_idx[b * 512 + t] = idxs[t];
}

// ---------------- windowed attention via MFMA (bf16 inputs) ----------------
__global__ __launch_bounds__(256) void attn_mfma(const u16* __restrict__ qkb,
                                                 const u16* __restrict__ vtb,
                                                 const float* __restrict__ ts,
                                                 u16* __restrict__ ctx) {
    __shared__ __align__(16) u16 Ks[160 * 64];      // XOR-swizzled [key][dim]
    __shared__ __align__(16) u16 Vt[64][168];       // [dim][key] pad->168
    __shared__ float lts[160];
    __shared__ __align__(16) u16 Pw[4][16 * 40];    // per-wave P round-trip, stride 40
    int qt = blockIdx.x, h = blockIdx.y, b = blockIdx.z;
    int tid = threadIdx.x, wave = tid >> 6, lane = tid & 63;
    int l15 = lane & 15, l4 = lane >> 4;
    int qbase = qt * 64 + wave * 16;
    int jbase0 = qt * 64 - 128;

    s16x8 qaf[2];
    {
        const u16* qp = qkb + (size_t)(b * L_ + qbase + l15) * 1536 + h * HD_;
        qaf[0] = *(const s16x8*)(qp + l4 * 8);
        qaf[1] = *(const s16x8*)(qp + 32 + l4 * 8);
    }
    f32x4 oacc[4] = {};
    float sums[4] = {0.f, 0.f, 0.f, 0.f};
    const u16* vbase = vtb + (size_t)(b * H_ + h) * HD_ * L_;

    for (int half = 0; half < 2; ++half) {
        int jbase = jbase0 + half * 160;
        __syncthreads();
        // K: async global->LDS (linear dest, pre-swizzled source)
        #pragma unroll
        for (int i = 0; i < 5; ++i) {
            int rbase = (wave * 5 + i) * 8;
            int row = rbase + (lane >> 3);
            int gc = (lane & 7) ^ (row & 7);
            int jc = min(max(jbase + row, 0), L_ - 1);
            gload_lds16(qkb + (size_t)(b * L_ + jc) * 1536 + 768 + h * HD_ + gc * 8, &Ks[rbase * 64]);
        }
        // V: coalesced bf16 rows from vtb -> padded Vt
        #pragma unroll
        for (int i = 0; i < 5; ++i) {
            int c = tid + 256 * i;          // 0..1279
            int d = c / 20, ch = c % 20;
            int tok0 = min(max(jbase + ch * 8, 0), L_ - 8);
            s16x8 v = *(const s16x8*)(vbase + (size_t)d * L_ + tok0);
            *(s16x8*)&Vt[d][ch * 8] = v;
        }
        if (tid < 160) {
            int jc = min(max(jbase + tid, 0), L_ - 1);
            lts[tid] = __logf(fmaxf(ts[b * L_ + jc], 1e-8f));
        }
        __syncthreads();
        #pragma unroll
        for (int kb = 0; kb < 5; ++kb) {
            #pragma unroll
            for (int f = 0; f < 2; ++f) {
                int kf16 = kb * 32 + f * 16;
                f32x4 s = {};
                #pragma unroll
                for (int c = 0; c < 2; ++c) {
                    int row = kf16 + l15;
                    int ch = (c * 4 + l4) ^ (row & 7);
                    s16x8 kf = *(const s16x8*)&Ks[row * 64 + ch * 8];
                    s = __builtin_amdgcn_mfma_f32_16x16x32_bf16(qaf[c], kf, s, 0, 0, 0);
                }
                int j = jbase + kf16 + l15;
                float lt = lts[kf16 + l15];
                #pragma unroll
                for (int jj = 0; jj < 4; ++jj) {
                    int q = qbase + l4 * 4 + jj;
                    int d = j - q;
                    bool ok = (j >= 0) && (j < L_) && (d >= -128) && (d <= 128);
                    float p = ok ? __expf(s[jj] * 0.125f + lt) : 0.f;
                    sums[jj] += p;
                    Pw[wave][(l4 * 4 + jj) * 40 + f * 16 + l15] = f2bf(p);
                }
            }
            asm volatile("s_waitcnt lgkmcnt(0)" ::: "memory");
            s16x8 paf = *(const s16x8*)&Pw[wave][l15 * 40 + l4 * 8];
            #pragma unroll
            for (int df = 0; df < 4; ++df) {
                s16x8 vbf = *(const s16x8*)&Vt[df * 16 + l15][kb * 32 + l4 * 8];
                oacc[df] = __builtin_amdgcn_mfma_f32_16x16x32_bf16(paf, vbf, oacc[df], 0, 0, 0);
            }
        }
    }
    #pragma unroll
    for (int jj = 0; jj < 4; ++jj) {
        float s = sums[jj];
        s += __shfl_xor(s, 1); s += __shfl_xor(s, 2);
        s += __shfl_xor(s, 4); s += __shfl_xor(s, 8);
        sums[jj] = 1.f / s;
    }
    #pragma unroll
    for (int jj = 0; jj < 4; ++jj) {
        int q = qbase + l4 * 4 + jj;
        u16* crow = ctx + (size_t)(b * L_ + q) * D_ + h * HD_;
        #pragma unroll
        for (int df = 0; df < 4; ++df)
            crow[df * 16 + l15] = f2bf(oacc[df][jj] * sums[jj]);
    }
}

// ---------------- merge kernels (fused proj split-K reduce: xm = sum parts + bproj + x) ----------------
#define PMN4 (B_ * L_ * D_ / 4)   // one proj partial in float4s

__device__ __forceinline__ float4 proj_row4(const float* __restrict__ pp,
                                            const float* __restrict__ bproj,
                                            const float* __restrict__ x,
                                            int tok /*0..B*L-1*/, int t /*0..191*/) {
    size_t base = (size_t)tok * (D_ / 4) + t;
    float4 s = ((const float4*)pp)[base];
    float4 v1 = ((const float4*)pp)[PMN4 + base];
    float4 v2 = ((const float4*)pp)[2 * (size_t)PMN4 + base];
    float4 bv = ((const float4*)bproj)[t];
    float4 xv = ((const float4*)x)[base];
    s.x += v1.x + v2.x + bv.x + xv.x;
    s.y += v1.y + v2.y + bv.y + xv.y;
    s.z += v1.z + v2.z + bv.z + xv.z;
    s.w += v1.w + v2.w + bv.w + xv.w;
    return s;
}

__global__ __launch_bounds__(256) void merge_init(const float* __restrict__ pp,
                                                  const float* __restrict__ bproj,
                                                  const float* __restrict__ x,
                                                  const float* __restrict__ ts,
                                                  const int* __restrict__ unm_idx,
                                                  float* __restrict__ x_sum, float* __restrict__ s_new) {
    int row = blockIdx.x;
    int b = row / LN_, rl = row % LN_;
    int srcTok = (rl < 512) ? (2 * unm_idx[b * 512 + rl]) : (2 * (rl - 512) + 1);
    float tsv = ts[b * L_ + srcTok];
    int t = threadIdx.x;
    if (t < 192) {
        float4 v = proj_row4(pp, bproj, x, b * L_ + srcTok, t);
        v.x *= tsv; v.y *= tsv; v.z *= tsv; v.w *= tsv;
        ((float4*)(x_sum + (size_t)(b * LN_ + rl) * D_))[t] = v;
    }
    if (t == 0) s_new[b * LN_ + rl] = tsv;
}

__global__ __launch_bounds__(256) void merge_scatter(const float* __restrict__ pp,
                                                     const float* __restrict__ bproj,
                                                     const float* __restrict__ x,
                                                     const float* __restrict__ ts,
                                                     const int* __restrict__ src_idx, const int* __restrict__ dst_idx,
                                                     float* __restrict__ x_sum, float* __restrict__ s_new) {
    int e = blockIdx.x;
    int b = e >> 9, el = e & 511;
    int s = src_idx[b * 512 + el];
    int dtok = dst_idx[b * 512 + el];
    int srcTok = 2 * s;
    float tsv = ts[b * L_ + srcTok];
    float* dst = x_sum + (size_t)(b * LN_ + 512 + dtok) * D_;
    int t = threadIdx.x;
    if (t < 192) {
        float4 v = proj_row4(pp, bproj, x, b * L_ + srcTok, t);
        atomicAdd(&dst[4 * t + 0], v.x * tsv);
        atomicAdd(&dst[4 * t + 1], v.y * tsv);
        atomicAdd(&dst[4 * t + 2], v.z * tsv);
        atomicAdd(&dst[4 * t + 3], v.w * tsv);
    }
    if (t == 0) atomicAdd(&s_new[b * LN_ + 512 + dtok], tsv);
}

__global__ __launch_bounds__(256) void merge_div(float* __restrict__ x_sum, const float* __restrict__ s_new) {
    int row = blockIdx.x;
    float inv = 1.f / (s_new[row] + 1e-8f);
    float* p = x_sum + (size_t)row * D_;
    int t = threadIdx.x;
    if (t < 192) {
        float4 v = ((float4*)p)[t];
        v.x *= inv; v.y *= inv; v.z *= inv; v.w *= inv;
        ((float4*)p)[t] = v;
    }
}

extern "C" void kernel_launch(void* const* d_in, const int* in_sizes, int n_in,
                              void* d_out, int out_size, void* d_ws, size_t ws_size,
                              hipStream_t stream) {
    (void)in_sizes; (void)n_in; (void)out_size; (void)ws_size;
    const float* x     = (const float*)d_in[0];
    const float* ts    = (const float*)d_in[1];
    const float* ln1g  = (const float*)d_in[2];
    const float* ln1b  = (const float*)d_in[3];
    const float* ln2g  = (const float*)d_in[4];
    const float* ln2b  = (const float*)d_in[5];
    const float* Wqkv  = (const float*)d_in[6];
    const float* bqkv  = (const float*)d_in[7];
    const float* Wproj = (const float*)d_in[8];
    const float* bproj = (const float*)d_in[9];
    const float* W1    = (const float*)d_in[10];
    const float* b1    = (const float*)d_in[11];
    const float* W2    = (const float*)d_in[12];
    const float* b2    = (const float*)d_in[13];
    float* out = (float*)d_out;

    char* ws = (char*)d_ws;
    float* h_f32   = (float*)(ws + 0);            // 12582912  (LN1 f32; dead after kmerge)
    u16*   h_bf16  = (u16*)(ws + 12582912);       // 6291456   (LN1 bf16 -> reused as ctx)
    u16*   qkb     = (u16*)(ws + 18874368);       // 12582912  [4096][1536] bf16 (dead after attn)
    u16*   vtb     = (u16*)(ws + 31457280);       // 6291456   [2][12][64][2048] bf16 (dead after attn)
    u16*   mid     = (u16*)(ws + 37748736);       // 18874368  [3072][3072] bf16 (MLP1 out)
    float* x_new   = (float*)(ws + 56623104);     // 9437184
    float* s_new   = (float*)(ws + 66060288);     // 12288
    u16*   h2      = (u16*)(ws + 66072576);       // 4718592
    u16*   WqkvT   = (u16*)(ws + 70791168);       // 3538944
    u16*   WprojT  = (u16*)(ws + 74330112);       // 1179648
    u16*   W1T     = (u16*)(ws + 75509760);       // 4718592
    u16*   W2T     = (u16*)(ws + 80228352);       // 4718592
    float* wkm     = (float*)(ws + 84946944);     // 196608
    float* bkm     = (float*)(ws + 85143552);     // 256
    float* aset    = (float*)(ws + 85143808);     // 524288
    float* bset    = (float*)(ws + 85668096);     // 524288
    float* nmax    = (float*)(ws + 86192384);     // 8192
    int*   nidx    = (int*)(ws + 86200576);       // 8192
    int*   src_idx = (int*)(ws + 86208768);       // 4096
    int*   dst_idx = (int*)(ws + 86212864);       // 4096
    int*   unm_idx = (int*)(ws + 86216960);       // 4096
    u16*   ctx = h_bf16;
    // split-K partial buffers (aliased over dead regions; no temporal overlap):
    float* pparts  = (float*)(ws + 18874368);     // proj: 3 x 12582912 over qkb+vtb+mid[0:18.9MB]
    float* m2parts = (float*)(ws + 0);            // mlp2: 4 x 9437184 over h_f32+ctx+qkb+vtb

    ln_kernel<<<B_ * L_, 256, 0, stream>>>(x, ln1g, ln1b, h_f32, h_bf16, 1);
    build_wkm<<<192, 256, 0, stream>>>(Wqkv, bqkv, wkm, bkm);
    transpose_cast<<<dim3(3 * D_ / 32, D_ / 32), dim3(32, 8), 0, stream>>>(Wqkv, WqkvT, D_, 3 * D_);
    // QKV GEMM -> qk bf16 row-major + V transposed
    gemm_bf16<<<dim3(3 * D_ / BN, B_ * L_ / BM, 1), 256, 0, stream>>>(
        h_bf16, WqkvT, bqkv, nullptr, nullptr, qkb, vtb, B_ * L_, 3 * D_, D_, 4);
    kmerge_kn<<<B_ * L_ / 16, 256, 0, stream>>>(h_f32, wkm, bkm, aset, bset);
    tome_scores<<<dim3(256, B_), 256, 0, stream>>>(aset, bset, nmax, nidx);
    tome_sort<<<B_, 512, 0, stream>>>(nmax, nidx, src_idx, dst_idx, unm_idx);
    attn_mfma<<<dim3(L_ / 64, H_, B_), 256, 0, stream>>>(qkb, vtb, ts, ctx);
    transpose_cast<<<dim3(D_ / 32, D_ / 32), dim3(32, 8), 0, stream>>>(Wproj, WprojT, D_, D_);
    // proj GEMM: split-K=3 -> partial buffers (reduce fused into merge kernels)
    gemm_bf16<<<dim3(D_ / BN, B_ * L_ / BM, 3), 256, 0, stream>>>(
        ctx, WprojT, nullptr, nullptr, pparts, nullptr, nullptr, B_ * L_, D_, D_, 0);
    merge_init<<<B_ * LN_, 256, 0, stream>>>(pparts, bproj, x, ts, unm_idx, x_new, s_new);
    merge_scatter<<<B_ * 512, 256, 0, stream>>>(pparts, bproj, x, ts, src_idx, dst_idx, x_new, s_new);
    merge_div<<<B_ * LN_, 256, 0, stream>>>(x_new, s_new);
    ln_kernel<<<B_ * LN_, 256, 0, stream>>>(x_new, ln2g, ln2b, nullptr, h2, 0);
    transpose_cast<<<dim3(HID_ / 32, D_ / 32), dim3(32, 8), 0, stream>>>(W1, W1T, D_, HID_);
    gemm_bf16<<<dim3(HID_ / BN, B_ * LN_ / BM, 1), 256, 0, stream>>>(
        h2, W1T, b1, nullptr, nullptr, mid, nullptr, B_ * LN_, HID_, D_, 3);
    transpose_cast<<<dim3(D_ / 32, HID_ / 32), dim3(32, 8), 0, stream>>>(W2, W2T, HID_, D_);
    // MLP2 GEMM: split-K=4 -> partial buffers, then reduce (+b2 +x_new) -> out
    gemm_bf16<<<dim3(D_ / BN, B_ * LN_ / BM, 4), 256, 0, stream>>>(
        mid, W2T, nullptr, nullptr, m2parts, nullptr, nullptr, B_ * LN_, D_, HID_, 0);
    reduce_splitk<<<(B_ * LN_ * D_ / 4 + 255) / 256, 256, 0, stream>>>(
        m2parts, b2, x_new, out, 4, B_ * LN_ * D_ / 4, D_ / 4, B_ * LN_ * D_ / 4);
}

// Round 6
// 310.239 us; speedup vs baseline: 2.5912x; 1.0408x over previous
//
#include <hip/hip_runtime.h>
#include <hip/hip_bf16.h>

typedef __attribute__((ext_vector_type(4))) float f32x4;
typedef __attribute__((ext_vector_type(8))) short s16x8;
typedef unsigned short u16;

#define B_   2
#define L_   2048
#define D_   768
#define H_   12
#define HD_  64
#define LN_  1536   // merged length: 512 unm + 1024 dst
#define HID_ 3072

__device__ __forceinline__ u16 f2bf(float f) {
    union { float f; unsigned u; } v; v.f = f;
    unsigned r = (v.u + 0x7FFFu + ((v.u >> 16) & 1u)) >> 16;
    return (u16)r;
}

__device__ __forceinline__ void gload_lds16(const void* g, void* l) {
    __builtin_amdgcn_global_load_lds((const __attribute__((address_space(1))) void*)g,
                                     (__attribute__((address_space(3))) void*)l, 16, 0, 0);
}

#define WAITV(n) asm volatile("s_waitcnt vmcnt(" #n ")" ::: "memory")

// ---------------- LayerNorm (row = 768) ----------------
__global__ __launch_bounds__(256) void ln_kernel(const float* __restrict__ x,
                                                 const float* __restrict__ g,
                                                 const float* __restrict__ bb,
                                                 float* __restrict__ hf,
                                                 u16* __restrict__ hb,
                                                 int storeF32) {
    __shared__ float sm[8];
    int row = blockIdx.x;
    const float* xr = x + (size_t)row * D_;
    int t = threadIdx.x;
    float4 v = make_float4(0.f, 0.f, 0.f, 0.f);
    float s = 0.f, s2 = 0.f;
    if (t < 192) {
        v = ((const float4*)xr)[t];
        s = v.x + v.y + v.z + v.w;
        s2 = v.x * v.x + v.y * v.y + v.z * v.z + v.w * v.w;
    }
    for (int o = 32; o; o >>= 1) { s += __shfl_down(s, o); s2 += __shfl_down(s2, o); }
    int wv = t >> 6, ln = t & 63;
    if (ln == 0) { sm[wv] = s; sm[4 + wv] = s2; }
    __syncthreads();
    if (t == 0) { sm[0] = sm[0] + sm[1] + sm[2] + sm[3]; sm[4] = sm[4] + sm[5] + sm[6] + sm[7]; }
    __syncthreads();
    float mu = sm[0] * (1.f / D_);
    float var = sm[4] * (1.f / D_) - mu * mu;
    float rs = rsqrtf(var + 1e-5f);
    if (t < 192) {
        float4 gg = ((const float4*)g)[t], bv = ((const float4*)bb)[t];
        float4 o;
        o.x = (v.x - mu) * rs * gg.x + bv.x;
        o.y = (v.y - mu) * rs * gg.y + bv.y;
        o.z = (v.z - mu) * rs * gg.z + bv.z;
        o.w = (v.w - mu) * rs * gg.w + bv.w;
        if (storeF32) ((float4*)(hf + (size_t)row * D_))[t] = o;
        ushort4 u;
        u.x = f2bf(o.x); u.y = f2bf(o.y); u.z = f2bf(o.z); u.w = f2bf(o.w);
        ((ushort4*)(hb + (size_t)row * D_))[t] = u;
    }
}

// ---------------- transpose + cast fp32(RxC) -> bf16(CxR) ----------------
__global__ void transpose_cast(const float* __restrict__ in, u16* __restrict__ out, int R, int C) {
    __shared__ float tile[32][33];
    int c0 = blockIdx.x * 32, r0 = blockIdx.y * 32;
    int tx = threadIdx.x, ty = threadIdx.y; // 32 x 8
    for (int i = 0; i < 32; i += 8)
        tile[ty + i][tx] = in[(size_t)(r0 + ty + i) * C + c0 + tx];
    __syncthreads();
    for (int i = 0; i < 32; i += 8)
        out[(size_t)(c0 + ty + i) * R + r0 + tx] = f2bf(tile[tx][ty + i]);
}

// ---------------- split-K partial reduce: out = sum(parts) + bias + resid ----------------
__global__ __launch_bounds__(256) void reduce_splitk(const float* __restrict__ parts,
                                                     const float* __restrict__ bias,
                                                     const float* __restrict__ resid,
                                                     float* __restrict__ out,
                                                     int nparts, int MN4, int N4, int total4) {
    int i = blockIdx.x * 256 + threadIdx.x;
    if (i >= total4) return;
    float4 s = ((const float4*)parts)[i];
    for (int p = 1; p < nparts; ++p) {
        float4 v = ((const float4*)parts)[(size_t)p * MN4 + i];
        s.x += v.x; s.y += v.y; s.z += v.z; s.w += v.w;
    }
    float4 bv = ((const float4*)bias)[i % N4];
    s.x += bv.x; s.y += bv.y; s.z += bv.z; s.w += bv.w;
    if (resid) {
        float4 r = ((const float4*)resid)[i];
        s.x += r.x; s.y += r.y; s.z += r.z; s.w += r.w;
    }
    ((float4*)out)[i] = s;
}

// ================= 256x256 8-wave 4-phase-per-K-tile GEMM (T1+T2+T3+T4+T5) =================
// flags: 1=gelu, 2=bf16 out (Cb row-major, stride N), 4=qkv-split (Cb=[*,1536] qk bf16, Vt=v^T)
// Staging order per K-tile: Bh0,Bh1,Ah0,Ah1 (one half-tile per phase, 2 gload/thread each).
// Wait ledger (derived): phase0 vmcnt(4) [last tile: 2], phase2 vmcnt(6) [last tile: 0].
#define GBK 64
__global__ __launch_bounds__(512, 1) void gemm256(const u16* __restrict__ A, const u16* __restrict__ BT,
                                                  const float* __restrict__ bias,
                                                  u16* __restrict__ Cb, u16* __restrict__ Vt,
                                                  int M, int N, int K, int gridX, int flags) {
    __shared__ __align__(16) u16 lds[2][2][256 * GBK];   // [buf][0=A,1=B] : 128 KiB
    int tid = threadIdx.x;
    int wave = tid >> 6, lane = tid & 63;
    int wr = wave >> 2, wc = wave & 3;
    int l15 = lane & 15, l4 = lane >> 4;
    // bijective XCD swizzle (grid % 8 == 0 guaranteed by caller)
    int nwg = gridDim.x;
    int q8 = nwg >> 3;
    int bid = blockIdx.x;
    int wg = (bid & 7) * q8 + (bid >> 3);
    int mBase = (wg / gridX) * 256, nBase = (wg % gridX) * 256;

    f32x4 acc[8][4] = {};
    int nK = K / GBK;
    int lrow = lane >> 3, lsl = lane & 7;
    int gc8 = (lsl ^ lrow) * 8;          // row&7 == lane>>3 for 8-row groups

    auto stageHalf = [&](int buf, int op, int half, int kt) {
        const u16* src = op ? BT : A;
        int base = (op ? nBase : mBase) + half * 128;
        size_t koff = (size_t)kt * GBK;
        u16* dst = &lds[buf][op][half * 128 * GBK];
        #pragma unroll
        for (int i = 0; i < 2; ++i) {
            int rbase = wave * 8 + i * 64;                 // wave-uniform 8-row group
            gload_lds16(src + (size_t)(base + rbase + lrow) * K + koff + gc8,
                        dst + rbase * GBK);
        }
    };

    // prologue: stage tile 0 (B0,B1,A0,A1)
    stageHalf(0, 1, 0, 0); stageHalf(0, 1, 1, 0);
    stageHalf(0, 0, 0, 0); stageHalf(0, 0, 1, 0);

    int c = 0;
    for (int kt = 0; kt < nK; ++kt) {
        bool hasNext = kt + 1 < nK;
        #pragma unroll
        for (int p = 0; p < 4; ++p) {
            if (hasNext) {
                int op = (p < 2) ? 1 : 0;
                stageHalf(c ^ 1, op, p & 1, kt + 1);
            }
            if (p == 0) { if (hasNext) WAITV(4); else WAITV(2); }
            if (p == 2) { if (hasNext) WAITV(6); else WAITV(0); }
            __builtin_amdgcn_s_barrier();
            int kk = p & 1, mh = p >> 1;
            s16x8 af[4], bf[4];
            #pragma unroll
            for (int i = 0; i < 4; ++i) {
                int mrow = wr * 128 + (mh * 4 + i) * 16 + l15;
                int ch = kk * 4 + l4;
                af[i] = *(const s16x8*)&lds[c][0][mrow * GBK + ((ch ^ (mrow & 7)) * 8)];
                int nrow = wc * 64 + i * 16 + l15;
                bf[i] = *(const s16x8*)&lds[c][1][nrow * GBK + ((ch ^ (nrow & 7)) * 8)];
            }
            __builtin_amdgcn_s_setprio(1);
            #pragma unroll
            for (int mi = 0; mi < 4; ++mi)
                #pragma unroll
                for (int ni = 0; ni < 4; ++ni)
                    acc[mh * 4 + mi][ni] = __builtin_amdgcn_mfma_f32_16x16x32_bf16(af[mi], bf[ni], acc[mh * 4 + mi][ni], 0, 0, 0);
            __builtin_amdgcn_s_setprio(0);
            __builtin_amdgcn_s_barrier();
        }
        c ^= 1;
    }

    if (flags & 4) {
        // QKV split: cols [0,1536) -> Cb row-major (q|k) bf16; cols [1536,2304) -> Vt[b][h][d][tok]
        #pragma unroll
        for (int mi = 0; mi < 8; ++mi) {
            int r0 = mBase + wr * 128 + mi * 16 + l4 * 4;
            #pragma unroll
            for (int ni = 0; ni < 4; ++ni) {
                int c0 = nBase + wc * 64 + ni * 16;
                int col = c0 + l15;
                float bv = bias[col];
                if (c0 < 1536) {
                    #pragma unroll
                    for (int j = 0; j < 4; ++j)
                        Cb[(size_t)(r0 + j) * 1536 + col] = f2bf(acc[mi][ni][j] + bv);
                } else {
                    int hh = (col - 1536) >> 6, dd = (col - 1536) & 63;
                    int bb2 = r0 >> 11, tok = r0 & 2047;
                    ushort4 u;
                    u.x = f2bf(acc[mi][ni][0] + bv);
                    u.y = f2bf(acc[mi][ni][1] + bv);
                    u.z = f2bf(acc[mi][ni][2] + bv);
                    u.w = f2bf(acc[mi][ni][3] + bv);
                    *(ushort4*)&Vt[(((size_t)bb2 * H_ + hh) * HD_ + dd) * (size_t)L_ + tok] = u;
                }
            }
        }
        return;
    }
    // gelu + bf16 out
    #pragma unroll
    for (int mi = 0; mi < 8; ++mi) {
        #pragma unroll
        for (int j = 0; j < 4; ++j) {
            int row = mBase + wr * 128 + mi * 16 + l4 * 4 + j;
            #pragma unroll
            for (int ni = 0; ni < 4; ++ni) {
                int col = nBase + wc * 64 + ni * 16 + l15;
                float v = acc[mi][ni][j] + bias[col];
                if (flags & 1) v = 0.5f * v * (1.f + erff(v * 0.70710678118654752f));
                Cb[(size_t)row * N + col] = f2bf(v);
            }
        }
    }
}

// ---------------- bf16 MFMA GEMM 128x128, 2-phase dbuf (used for split-K GEMMs) ----------------
#define BM 128
#define BN 128
#define BK 64
__global__ __launch_bounds__(256) void gemm_bf16(const u16* __restrict__ A, const u16* __restrict__ BT,
                                                 const float* __restrict__ bias,
                                                 const float* __restrict__ resid,
                                                 float* __restrict__ Cf, u16* __restrict__ Cb,
                                                 int M, int N, int K, int flags) {
    __shared__ __align__(16) u16 As[2 * BM * BK];
    __shared__ __align__(16) u16 Bs[2 * BM * BK];
    int tid = threadIdx.x;
    int wave = tid >> 6, lane = tid & 63;
    int wr = wave >> 1, wc = wave & 1;
    int mBase = blockIdx.y * BM, nBase = blockIdx.x * BN;
    int l15 = lane & 15, l4 = lane >> 4;
    f32x4 acc[4][4] = {};
    int Ksplit = K / gridDim.z;
    int kt0 = (blockIdx.z * Ksplit) / BK, kt1 = kt0 + Ksplit / BK;
    int lrow = lane >> 3, lsl = lane & 7;

    auto stage = [&](int kt, int buf) {
        size_t koff = (size_t)kt * BK;
        u16* as = &As[buf * BM * BK];
        u16* bs = &Bs[buf * BM * BK];
        #pragma unroll
        for (int i = 0; i < 4; ++i) {
            int rbase = wave * 32 + i * 8;
            int row = rbase + lrow;
            int gc = lsl ^ (row & 7);
            gload_lds16(A + (size_t)(mBase + row) * K + koff + gc * 8, &as[rbase * BK]);
            gload_lds16(BT + (size_t)(nBase + row) * K + koff + gc * 8, &bs[rbase * BK]);
        }
    };

    stage(kt0, 0);
    int cur = 0;
    for (int kt = kt0; kt < kt1; ++kt) {
        if (kt + 1 < kt1) {
            stage(kt + 1, cur ^ 1);
            WAITV(8);
        } else {
            WAITV(0);
        }
        __builtin_amdgcn_s_barrier();
        const u16* as = &As[cur * BM * BK];
        const u16* bs = &Bs[cur * BM * BK];
        #pragma unroll
        for (int kk = 0; kk < 2; ++kk) {
            s16x8 af[4], bf[4];
            #pragma unroll
            for (int mi = 0; mi < 4; ++mi) {
                int row = wr * 64 + mi * 16 + l15;
                int ch = kk * 4 + l4;
                af[mi] = *(const s16x8*)(&as[row * BK + (ch ^ (row & 7)) * 8]);
            }
            #pragma unroll
            for (int ni = 0; ni < 4; ++ni) {
                int row = wc * 64 + ni * 16 + l15;
                int ch = kk * 4 + l4;
                bf[ni] = *(const s16x8*)(&bs[row * BK + (ch ^ (row & 7)) * 8]);
            }
            #pragma unroll
            for (int mi = 0; mi < 4; ++mi)
                #pragma unroll
                for (int ni = 0; ni < 4; ++ni)
                    acc[mi][ni] = __builtin_amdgcn_mfma_f32_16x16x32_bf16(af[mi], bf[ni], acc[mi][ni], 0, 0, 0);
        }
        asm volatile("s_waitcnt lgkmcnt(0)" ::: "memory");
        __builtin_amdgcn_s_barrier();
        cur ^= 1;
    }

    if (gridDim.z > 1) {
        float* dst = Cf + (size_t)blockIdx.z * M * N;
        #pragma unroll
        for (int mi = 0; mi < 4; ++mi)
            #pragma unroll
            for (int j = 0; j < 4; ++j) {
                int row = mBase + wr * 64 + mi * 16 + l4 * 4 + j;
                #pragma unroll
                for (int ni = 0; ni < 4; ++ni) {
                    int col = nBase + wc * 64 + ni * 16 + l15;
                    dst[(size_t)row * N + col] = acc[mi][ni][j];
                }
            }
        return;
    }
    #pragma unroll
    for (int mi = 0; mi < 4; ++mi) {
        #pragma unroll
        for (int j = 0; j < 4; ++j) {
            int row = mBase + wr * 64 + mi * 16 + l4 * 4 + j;
            #pragma unroll
            for (int ni = 0; ni < 4; ++ni) {
                int col = nBase + wc * 64 + ni * 16 + l15;
                float v = acc[mi][ni][j] + bias[col];
                if (resid) v += resid[(size_t)row * N + col];
                if (flags & 1) v = 0.5f * v * (1.f + erff(v * 0.70710678118654752f));
                if (flags & 2) Cb[(size_t)row * N + col] = f2bf(v);
                else Cf[(size_t)row * N + col] = v;
            }
        }
    }
}

// ---------------- build mean-of-head-blocks Wk / bk ----------------
__global__ void build_wkm(const float* __restrict__ Wqkv, const float* __restrict__ bqkv,
                          float* __restrict__ wkm /*[768][64]*/, float* __restrict__ bkm) {
    int idx = blockIdx.x * 256 + threadIdx.x;
    if (idx < D_ * HD_) {
        int k = idx >> 6, c = idx & 63;
        float s = 0.f;
        #pragma unroll
        for (int hh = 0; hh < H_; ++hh) s += Wqkv[(size_t)k * (3 * D_) + D_ + hh * HD_ + c];
        wkm[idx] = s * (1.f / H_);
    }
    if (idx < HD_) {
        float s = 0.f;
        #pragma unroll
        for (int hh = 0; hh < H_; ++hh) s += bqkv[D_ + hh * HD_ + idx];
        bkm[idx] = s * (1.f / H_);
    }
}

// ---------------- k_merge + normalize + even/odd split (fp32) ----------------
__global__ __launch_bounds__(256) void kmerge_kn(const float* __restrict__ hf, const float* __restrict__ wkm,
                                                 const float* __restrict__ bkm,
                                                 float* __restrict__ aset, float* __restrict__ bset) {
    __shared__ float wtile[256 * 64]; // 64KB
    int t = threadIdx.x, wave = t >> 6, lane = t & 63;
    int m0 = blockIdx.x * 16 + wave * 4;
    float acc[4] = {0.f, 0.f, 0.f, 0.f};
    for (int kc = 0; kc < 3; ++kc) {
        __syncthreads();
        for (int i = t; i < 256 * 64 / 4; i += 256)
            ((float4*)wtile)[i] = ((const float4*)(wkm + kc * 256 * 64))[i];
        __syncthreads();
        for (int k = 0; k < 256; ++k) {
            float wv = wtile[k * 64 + lane];
            #pragma unroll
            for (int r = 0; r < 4; ++r)
                acc[r] = fmaf(hf[(size_t)(m0 + r) * D_ + kc * 256 + k], wv, acc[r]);
        }
    }
    #pragma unroll
    for (int r = 0; r < 4; ++r) {
        float v = acc[r] + bkm[lane];
        float n2 = v * v;
        for (int o = 32; o; o >>= 1) n2 += __shfl_xor(n2, o);
        float kn = v / (sqrtf(n2) + 1e-8f);
        int m = m0 + r;
        int bb = m >> 11, l = m & 2047;
        float* dp = (l & 1) ? bset : aset;
        dp[((size_t)bb * 1024 + (l >> 1)) * 64 + lane] = kn;
    }
}

// ---------------- ToMe scores: rowwise max+argmax over 1024 cols ----------------
__global__ __launch_bounds__(256) void tome_scores(const float* __restrict__ aset, const float* __restrict__ bset,
                                                   float* __restrict__ node_max, int* __restrict__ node_idx) {
    __shared__ float aves[4][64];
    __shared__ unsigned long long wmax[4][4];
    int b = blockIdx.y;
    int a0 = blockIdx.x * 4;
    int t = threadIdx.x;
    { int r = t >> 6, d = t & 63; aves[r][d] = aset[((size_t)b * 1024 + a0 + r) * 64 + d]; }
    __syncthreads();
    unsigned long long best[4] = {0ull, 0ull, 0ull, 0ull};
    for (int c = t; c < 1024; c += 256) {
        const float4* brow = (const float4*)(bset + ((size_t)b * 1024 + c) * 64);
        float dot[4] = {0.f, 0.f, 0.f, 0.f};
        #pragma unroll
        for (int i = 0; i < 16; ++i) {
            float4 bv = brow[i];
            #pragma unroll
            for (int r = 0; r < 4; ++r) {
                dot[r] = fmaf(aves[r][4 * i + 0], bv.x, dot[r]);
                dot[r] = fmaf(aves[r][4 * i + 1], bv.y, dot[r]);
                dot[r] = fmaf(aves[r][4 * i + 2], bv.z, dot[r]);
                dot[r] = fmaf(aves[r][4 * i + 3], bv.w, dot[r]);
            }
        }
        #pragma unroll
        for (int r = 0; r < 4; ++r) {
            unsigned bits = __float_as_uint(dot[r]);
            unsigned u = (bits & 0x80000000u) ? ~bits : (bits | 0x80000000u);
            unsigned long long key = ((unsigned long long)u << 32) | (unsigned)(0xFFFFFFFFu - (unsigned)c);
            best[r] = best[r] > key ? best[r] : key;
        }
    }
    int wv = t >> 6, ln = t & 63;
    #pragma unroll
    for (int r = 0; r < 4; ++r) {
        unsigned long long v = best[r];
        for (int o = 32; o; o >>= 1) {
            unsigned long long w = __shfl_xor(v, o);
            v = v > w ? v : w;
        }
        if (ln == 0) wmax[r][wv] = v;
    }
    __syncthreads();
    if (t == 0) {
        for (int r = 0; r < 4; ++r) {
            int a = a0 + r;
            unsigned long long m = wmax[r][0];
            for (int w = 1; w < 4; ++w) m = m > wmax[r][w] ? m : wmax[r][w];
            float val; int idx;
            if (a == 0) { val = -INFINITY; idx = 0; }
            else {
                unsigned u = (unsigned)(m >> 32);
                unsigned bits = (u & 0x80000000u) ? (u ^ 0x80000000u) : ~u;
                val = __uint_as_float(bits);
                idx = (int)(0xFFFFFFFFu - (unsigned)(m & 0xFFFFFFFFu));
            }
            node_max[b * 1024 + a] = val;
            node_idx[b * 1024 + a] = idx;
        }
    }
}

// ---------------- stable argsort (desc value, asc idx) + unm sort ----------------
__global__ __launch_bounds__(512) void tome_sort(const float* __restrict__ node_max, const int* __restrict__ node_idx,
                                                 int* __restrict__ src_idx, int* __restrict__ dst_idx,
                                                 int* __restrict__ unm_idx) {
    __shared__ unsigned long long keys[1024];
    __shared__ int idxs[512];
    int b = blockIdx.x, t = threadIdx.x;
    for (int i = t; i < 1024; i += 512) {
        float v = node_max[b * 1024 + i];
        unsigned bits = __float_as_uint(v);
        unsigned u = (bits & 0x80000000u) ? ~bits : (bits | 0x80000000u);
        keys[i] = ((unsigned long long)(~u) << 32) | (unsigned)i; // ascending == desc value, asc idx
    }
    __syncthreads();
    for (int k = 2; k <= 1024; k <<= 1)
        for (int j = k >> 1; j > 0; j >>= 1) {
            for (int i = t; i < 1024; i += 512) {
                int ixj = i ^ j;
                if (ixj > i) {
                    bool up = (i & k) == 0;
                    unsigned long long a = keys[i], c = keys[ixj];
                    if (up ? (a > c) : (a < c)) { keys[i] = c; keys[ixj] = a; }
                }
            }
            __syncthreads();
        }
    {
        int s = (int)(keys[t] & 0xFFFFFFFFu);
        src_idx[b * 512 + t] = s;
        dst_idx[b * 512 + t] = node_idx[b * 1024 + s];
        idxs[t] = (int)(keys[512 + t] & 0xFFFFFFFFu);
    }
    __syncthreads();
    for (int k = 2; k <= 512; k <<= 1)
        for (int j = k >> 1; j > 0; j >>= 1) {
            int i = t, ixj = t ^ j;
            if (ixj > i) {
                bool up = (i & k) == 0;
                int a = idxs[i], c = idxs[ixj];
                if (up ? (a > c) : (a < c)) { idxs[i] = c; idxs[ixj] = a; }
            }
            __syncthreads();
        }
    unm_idx[b * 512 + t] = idxs[t];
}

// ---------------- windowed attention via MFMA (bf16 inputs) ----------------
__global__ __launch_bounds__(256) void attn_mfma(const u16* __restrict__ qkb,
                                                 const u16* __restrict__ vtb,
                                                 const float* __restrict__ ts,
                                                 u16* __restrict__ ctx) {
    __shared__ __align__(16) u16 Ks[160 * 64];      // XOR-swizzled [key][dim]
    __shared__ __align__(16) u16 Vt[64][168];       // [dim][key] pad->168
    __shared__ float lts[160];
    __shared__ __align__(16) u16 Pw[4][16 * 40];    // per-wave P round-trip, stride 40
    int qt = blockIdx.x, h = blockIdx.y, b = blockIdx.z;
    int tid = threadIdx.x, wave = tid >> 6, lane = tid & 63;
    int l15 = lane & 15, l4 = lane >> 4;
    int qbase = qt * 64 + wave * 16;
    int jbase0 = qt * 64 - 128;

    s16x8 qaf[2];
    {
        const u16* qp = qkb + (size_t)(b * L_ + qbase + l15) * 1536 + h * HD_;
        qaf[0] = *(const s16x8*)(qp + l4 * 8);
        qaf[1] = *(const s16x8*)(qp + 32 + l4 * 8);
    }
    f32x4 oacc[4] = {};
    float sums[4] = {0.f, 0.f, 0.f, 0.f};
    const u16* vbase = vtb + (size_t)(b * H_ + h) * HD_ * L_;

    for (int half = 0; half < 2; ++half) {
        int jbase = jbase0 + half * 160;
        __syncthreads();
        #pragma unroll
        for (int i = 0; i < 5; ++i) {
            int rbase = (wave * 5 + i) * 8;
            int row = rbase + (lane >> 3);
            int gc = (lane & 7) ^ (row & 7);
            int jc = min(max(jbase + row, 0), L_ - 1);
            gload_lds16(qkb + (size_t)(b * L_ + jc) * 1536 + 768 + h * HD_ + gc * 8, &Ks[rbase * 64]);
        }
        #pragma unroll
        for (int i = 0; i < 5; ++i) {
            int c = tid + 256 * i;          // 0..1279
            int d = c / 20, ch = c % 20;
            int tok0 = min(max(jbase + ch * 8, 0), L_ - 8);
            s16x8 v = *(const s16x8*)(vbase + (size_t)d * L_ + tok0);
            *(s16x8*)&Vt[d][ch * 8] = v;
        }
        if (tid < 160) {
            int jc = min(max(jbase + tid, 0), L_ - 1);
            lts[tid] = __logf(fmaxf(ts[b * L_ + jc], 1e-8f));
        }
        __syncthreads();
        #pragma unroll
        for (int kb = 0; kb < 5; ++kb) {
            #pragma unroll
            for (int f = 0; f < 2; ++f) {
                int kf16 = kb * 32 + f * 16;
                f32x4 s = {};
                #pragma unroll
                for (int c = 0; c < 2; ++c) {
                    int row = kf16 + l15;
                    int ch = (c * 4 + l4) ^ (row & 7);
                    s16x8 kf = *(const s16x8*)&Ks[row * 64 + ch * 8];
                    s = __builtin_amdgcn_mfma_f32_16x16x32_bf16(qaf[c], kf, s, 0, 0, 0);
                }
                int j = jbase + kf16 + l15;
                float lt = lts[kf16 + l15];
                #pragma unroll
                for (int jj = 0; jj < 4; ++jj) {
                    int q = qbase + l4 * 4 + jj;
                    int d = j - q;
                    bool ok = (j >= 0) && (j < L_) && (d >= -128) && (d <= 128);
                    float p = ok ? __expf(s[jj] * 0.125f + lt) : 0.f;
                    sums[jj] += p;
                    Pw[wave][(l4 * 4 + jj) * 40 + f * 16 + l15] = f2bf(p);
                }
            }
            asm volatile("s_waitcnt lgkmcnt(0)" ::: "memory");
            s16x8 paf = *(const s16x8*)&Pw[wave][l15 * 40 + l4 * 8];
            #pragma unroll
            for (int df = 0; df < 4; ++df) {
                s16x8 vbf = *(const s16x8*)&Vt[df * 16 + l15][kb * 32 + l4 * 8];
                oacc[df] = __builtin_amdgcn_mfma_f32_16x16x32_bf16(paf, vbf, oacc[df], 0, 0, 0);
            }
        }
    }
    #pragma unroll
    for (int jj = 0; jj < 4; ++jj) {
        float s = sums[jj];
        s += __shfl_xor(s, 1); s += __shfl_xor(s, 2);
        s += __shfl_xor(s, 4); s += __shfl_xor(s, 8);
        sums[jj] = 1.f / s;
    }
    #pragma unroll
    for (int jj = 0; jj < 4; ++jj) {
        int q = qbase + l4 * 4 + jj;
        u16* crow = ctx + (size_t)(b * L_ + q) * D_ + h * HD_;
        #pragma unroll
        for (int df = 0; df < 4; ++df)
            crow[df * 16 + l15] = f2bf(oacc[df][jj] * sums[jj]);
    }
}

// ---------------- merge kernels (fused proj split-K reduce: xm = sum parts + bproj + x) ----------------
#define PMN4 (B_ * L_ * D_ / 4)   // one proj partial in float4s

__device__ __forceinline__ float4 proj_row4(const float* __restrict__ pp,
                                            const float* __restrict__ bproj,
                                            const float* __restrict__ x,
                                            int tok /*0..B*L-1*/, int t /*0..191*/) {
    size_t base = (size_t)tok * (D_ / 4) + t;
    float4 s = ((const float4*)pp)[base];
    float4 v1 = ((const float4*)pp)[PMN4 + base];
    float4 v2 = ((const float4*)pp)[2 * (size_t)PMN4 + base];
    float4 bv = ((const float4*)bproj)[t];
    float4 xv = ((const float4*)x)[base];
    s.x += v1.x + v2.x + bv.x + xv.x;
    s.y += v1.y + v2.y + bv.y + xv.y;
    s.z += v1.z + v2.z + bv.z + xv.z;
    s.w += v1.w + v2.w + bv.w + xv.w;
    return s;
}

__global__ __launch_bounds__(256) void merge_init(const float* __restrict__ pp,
                                                  const float* __restrict__ bproj,
                                                  const float* __restrict__ x,
                                                  const float* __restrict__ ts,
                                                  const int* __restrict__ unm_idx,
                                                  float* __restrict__ x_sum, float* __restrict__ s_new) {
    int row = blockIdx.x;
    int b = row / LN_, rl = row % LN_;
    int srcTok = (rl < 512) ? (2 * unm_idx[b * 512 + rl]) : (2 * (rl - 512) + 1);
    float tsv = ts[b * L_ + srcTok];
    int t = threadIdx.x;
    if (t < 192) {
        float4 v = proj_row4(pp, bproj, x, b * L_ + srcTok, t);
        v.x *= tsv; v.y *= tsv; v.z *= tsv; v.w *= tsv;
        ((float4*)(x_sum + (size_t)(b * LN_ + rl) * D_))[t] = v;
    }
    if (t == 0) s_new[b * LN_ + rl] = tsv;
}

__global__ __launch_bounds__(256) void merge_scatter(const float* __restrict__ pp,
                                                     const float* __restrict__ bproj,
                                                     const float* __restrict__ x,
                                                     const float* __restrict__ ts,
                                                     const int* __restrict__ src_idx, const int* __restrict__ dst_idx,
                                                     float* __restrict__ x_sum, float* __restrict__ s_new) {
    int e = blockIdx.x;
    int b = e >> 9, el = e & 511;
    int s = src_idx[b * 512 + el];
    int dtok = dst_idx[b * 512 + el];
    int srcTok = 2 * s;
    float tsv = ts[b * L_ + srcTok];
    float* dst = x_sum + (size_t)(b * LN_ + 512 + dtok) * D_;
    int t = threadIdx.x;
    if (t < 192) {
        float4 v = proj_row4(pp, bproj, x, b * L_ + srcTok, t);
        atomicAdd(&dst[4 * t + 0], v.x * tsv);
        atomicAdd(&dst[4 * t + 1], v.y * tsv);
        atomicAdd(&dst[4 * t + 2], v.z * tsv);
        atomicAdd(&dst[4 * t + 3], v.w * tsv);
    }
    if (t == 0) atomicAdd(&s_new[b * LN_ + 512 + dtok], tsv);
}

__global__ __launch_bounds__(256) void merge_div(float* __restrict__ x_sum, const float* __restrict__ s_new) {
    int row = blockIdx.x;
    float inv = 1.f / (s_new[row] + 1e-8f);
    float* p = x_sum + (size_t)row * D_;
    int t = threadIdx.x;
    if (t < 192) {
        float4 v = ((float4*)p)[t];
        v.x *= inv; v.y *= inv; v.z *= inv; v.w *= inv;
        ((float4*)p)[t] = v;
    }
}

extern "C" void kernel_launch(void* const* d_in, const int* in_sizes, int n_in,
                              void* d_out, int out_size, void* d_ws, size_t ws_size,
                              hipStream_t stream) {
    (void)in_sizes; (void)n_in; (void)out_size; (void)ws_size;
    const float* x     = (const float*)d_in[0];
    const float* ts    = (const float*)d_in[1];
    const float* ln1g  = (const float*)d_in[2];
    const float* ln1b  = (const float*)d_in[3];
    const float* ln2g  = (const float*)d_in[4];
    const float* ln2b  = (const float*)d_in[5];
    const float* Wqkv  = (const float*)d_in[6];
    const float* bqkv  = (const float*)d_in[7];
    const float* Wproj = (const float*)d_in[8];
    const float* bproj = (const float*)d_in[9];
    const float* W1    = (const float*)d_in[10];
    const float* b1    = (const float*)d_in[11];
    const float* W2    = (const float*)d_in[12];
    const float* b2    = (const float*)d_in[13];
    float* out = (float*)d_out;

    char* ws = (char*)d_ws;
    float* h_f32   = (float*)(ws + 0);            // 12582912  (LN1 f32; dead after kmerge)
    u16*   h_bf16  = (u16*)(ws + 12582912);       // 6291456   (LN1 bf16 -> reused as ctx)
    u16*   qkb     = (u16*)(ws + 18874368);       // 12582912  [4096][1536] bf16 (dead after attn)
    u16*   vtb     = (u16*)(ws + 31457280);       // 6291456   [2][12][64][2048] bf16 (dead after attn)
    u16*   mid     = (u16*)(ws + 37748736);       // 18874368  [3072][3072] bf16 (MLP1 out)
    float* x_new   = (float*)(ws + 56623104);     // 9437184
    float* s_new   = (float*)(ws + 66060288);     // 12288
    u16*   h2      = (u16*)(ws + 66072576);       // 4718592
    u16*   WqkvT   = (u16*)(ws + 70791168);       // 3538944
    u16*   WprojT  = (u16*)(ws + 74330112);       // 1179648
    u16*   W1T     = (u16*)(ws + 75509760);       // 4718592
    u16*   W2T     = (u16*)(ws + 80228352);       // 4718592
    float* wkm     = (float*)(ws + 84946944);     // 196608
    float* bkm     = (float*)(ws + 85143552);     // 256
    float* aset    = (float*)(ws + 85143808);     // 524288
    float* bset    = (float*)(ws + 85668096);     // 524288
    float* nmax    = (float*)(ws + 86192384);     // 8192
    int*   nidx    = (int*)(ws + 86200576);       // 8192
    int*   src_idx = (int*)(ws + 86208768);       // 4096
    int*   dst_idx = (int*)(ws + 86212864);       // 4096
    int*   unm_idx = (int*)(ws + 86216960);       // 4096
    u16*   ctx = h_bf16;
    float* pparts  = (float*)(ws + 18874368);     // proj: 3 x 12582912 over qkb+vtb+mid[0:18.9MB]
    float* m2parts = (float*)(ws + 0);            // mlp2: 4 x 9437184 over h_f32+ctx+qkb+vtb

    ln_kernel<<<B_ * L_, 256, 0, stream>>>(x, ln1g, ln1b, h_f32, h_bf16, 1);
    build_wkm<<<192, 256, 0, stream>>>(Wqkv, bqkv, wkm, bkm);
    transpose_cast<<<dim3(3 * D_ / 32, D_ / 32), dim3(32, 8), 0, stream>>>(Wqkv, WqkvT, D_, 3 * D_);
    // QKV GEMM (256x256 8-phase) -> qk bf16 row-major + V transposed; grid 16x9=144 linear
    gemm256<<<(B_ * L_ / 256) * (3 * D_ / 256), 512, 0, stream>>>(
        h_bf16, WqkvT, bqkv, qkb, vtb, B_ * L_, 3 * D_, D_, 3 * D_ / 256, 4);
    kmerge_kn<<<B_ * L_ / 16, 256, 0, stream>>>(h_f32, wkm, bkm, aset, bset);
    tome_scores<<<dim3(256, B_), 256, 0, stream>>>(aset, bset, nmax, nidx);
    tome_sort<<<B_, 512, 0, stream>>>(nmax, nidx, src_idx, dst_idx, unm_idx);
    attn_mfma<<<dim3(L_ / 64, H_, B_), 256, 0, stream>>>(qkb, vtb, ts, ctx);
    transpose_cast<<<dim3(D_ / 32, D_ / 32), dim3(32, 8), 0, stream>>>(Wproj, WprojT, D_, D_);
    // proj GEMM: split-K=3 -> partial buffers (reduce fused into merge kernels)
    gemm_bf16<<<dim3(D_ / BN, B_ * L_ / BM, 3), 256, 0, stream>>>(
        ctx, WprojT, nullptr, nullptr, pparts, nullptr, B_ * L_, D_, D_, 0);
    merge_init<<<B_ * LN_, 256, 0, stream>>>(pparts, bproj, x, ts, unm_idx, x_new, s_new);
    merge_scatter<<<B_ * 512, 256, 0, stream>>>(pparts, bproj, x, ts, src_idx, dst_idx, x_new, s_new);
    merge_div<<<B_ * LN_, 256, 0, stream>>>(x_new, s_new);
    ln_kernel<<<B_ * LN_, 256, 0, stream>>>(x_new, ln2g, ln2b, nullptr, h2, 0);
    transpose_cast<<<dim3(HID_ / 32, D_ / 32), dim3(32, 8), 0, stream>>>(W1, W1T, D_, HID_);
    // MLP1 GEMM (256x256 8-phase) + gelu -> mid bf16; grid 12x12=144 linear
    gemm256<<<(B_ * LN_ / 256) * (HID_ / 256), 512, 0, stream>>>(
        h2, W1T, b1, mid, nullptr, B_ * LN_, HID_, D_, HID_ / 256, 3);
    transpose_cast<<<dim3(D_ / 32, HID_ / 32), dim3(32, 8), 0, stream>>>(W2, W2T, HID_, D_);
    // MLP2 GEMM: split-K=4 -> partial buffers, then reduce (+b2 +x_new) -> out
    gemm_bf16<<<dim3(D_ / BN, B_ * LN_ / BM, 4), 256, 0, stream>>>(
        mid, W2T, nullptr, nullptr, m2parts, nullptr, B_ * LN_, D_, HID_, 0);
    reduce_splitk<<<(B_ * LN_ * D_ / 4 + 255) / 256, 256, 0, stream>>>(
        m2parts, b2, x_new, out, 4, B_ * LN_ * D_ / 4, D_ / 4, B_ * LN_ * D_ / 4);
}